// Round 1
// 187.076 us; speedup vs baseline: 1.0387x; 1.0387x over previous
//
#include <hip/hip_runtime.h>
#include <math.h>

namespace {
constexpr int Tn = 128, Bn = 16, An = 32, OBS = 256, Kh = 3, NACT = 9, HID = 32;
constexpr int TBA = Tn * Bn * An;   // 65536 rows through the MLP
constexpr int BA  = Bn * An;        // 512 LSTM sequences
constexpr int OUT_LP  = TBA * Kh;         // 196608: logprobs start
constexpr int OUT_ENT = TBA * Kh + TBA;   // 262144: entropies start

// fp16 weight pack offsets (elements)
constexpr int W1_OFF  = 0;       // 128x256
constexpr int W2_OFF  = 32768;   // 128x128
constexpr int W3_OFF  = 49152;   // 64x128
constexpr int WIH_OFF = 57344;   // 128x64
constexpr int W16_TOT = 65536;

typedef __fp16   pk16x2 __attribute__((ext_vector_type(2)));  // builtin-compatible
typedef _Float16 half8v __attribute__((ext_vector_type(8)));
typedef float    f32x4  __attribute__((ext_vector_type(4)));
}

__device__ __forceinline__ float fast_sig(float x) {
  return __builtin_amdgcn_rcpf(1.f + __expf(-x));
}
__device__ __forceinline__ float fast_tanh(float x) {   // 2*sig(2x)-1, saturates safely
  return fmaf(2.f, fast_sig(2.f * x), -1.f);
}
__device__ __forceinline__ unsigned h2bits(pk16x2 h) {
  return __builtin_bit_cast(unsigned, h);
}
__device__ __forceinline__ pk16x2 bits2h(unsigned u) {
  return __builtin_bit_cast(pk16x2, u);
}
__device__ __forceinline__ float dot2(pk16x2 a, pk16x2 b, float c) {
#if __has_builtin(__builtin_amdgcn_fdot2)
  return __builtin_amdgcn_fdot2(a, b, c, false);
#else
  c = fmaf((float)a.x, (float)b.x, c);
  return fmaf((float)a.y, (float)b.y, c);
#endif
}
// swap adjacent lanes (xor 1) via DPP quad_perm(1,0,3,2): VALU, no DS pipe
__device__ __forceinline__ float dpp_swap1(float x) {
  return __uint_as_float((unsigned)__builtin_amdgcn_mov_dpp(
      (int)__float_as_uint(x), 0xB1, 0xF, 0xF, true));
}

// ---------------------------------------------------------------------------
// Weight fp32->fp16 pre-conversion + actions echo (fused, one launch).
// ---------------------------------------------------------------------------
__global__ __launch_bounds__(256) void cvtw_act_kernel(
    const float* __restrict__ W1, const float* __restrict__ W2,
    const float* __restrict__ W3, const float* __restrict__ Wih,
    _Float16* __restrict__ w16, const int* __restrict__ actions,
    float* __restrict__ out)
{
  const int bid = blockIdx.x;
  if (bid < W16_TOT/256) {
    int i = bid * 256 + threadIdx.x;            // 0..65535
    float v;
    if (i < W2_OFF)       v = W1[i];
    else if (i < W3_OFF)  v = W2[i - W2_OFF];
    else if (i < WIH_OFF) v = W3[i - W3_OFF];
    else                  v = Wih[i - WIH_OFF];
    w16[i] = (_Float16)v;
  } else {
    int i = (bid - W16_TOT/256) * 256 + threadIdx.x;  // 0..196607
    out[i] = (float)actions[i];
  }
}

// ---------------------------------------------------------------------------
// Fused MLP trunk + LSTM input projection, f16 MFMA (fp32 accumulate).
// v3: 512 threads (8 waves), 128 rows/block, 512 blocks -> halves per-row
// weight-staging traffic and barrier count. LDS 71.7 KB -> 2 blocks/CU.
// ---------------------------------------------------------------------------
template<int ROWS, int WSTR>
__device__ __forceinline__ void stage_wh(const _Float16* __restrict__ Wg, int kofs,
                                         _Float16* __restrict__ wt, int tid)
{
#pragma unroll
  for (int it = 0; it < ROWS/64; ++it) {        // ROWS*8 units / 512 threads
    int idx = tid + it*512;
    int o = idx >> 3, g8 = idx & 7;
    *(half8v*)&wt[o*72 + g8*8] =
        *(const half8v*)&Wg[(size_t)o*WSTR + kofs + g8*8];
  }
}

template<int NOC, int XSTR>
__device__ __forceinline__ void mfma_slab(const _Float16* __restrict__ xsrc,
                                          const _Float16* __restrict__ wt,
                                          int rA, int ln, int quad, f32x4 acc[8])
{
#pragma unroll
  for (int kc = 0; kc < 2; ++kc) {
    half8v a = *(const half8v*)&xsrc[rA*XSTR + kc*32 + quad*8];
#pragma unroll
    for (int oc = 0; oc < NOC; ++oc) {
      half8v b = *(const half8v*)&wt[(oc*16 + ln)*72 + kc*32 + quad*8];
      acc[oc] = __builtin_amdgcn_mfma_f32_16x16x32_f16(a, b, acc[oc], 0, 0, 0);
    }
  }
}

__global__ __launch_bounds__(512) void mlp_kernel(
    const float* __restrict__ x, const _Float16* __restrict__ w16,
    const float* __restrict__ b1, const float* __restrict__ b2,
    const float* __restrict__ b3, const float* __restrict__ bih,
    const float* __restrict__ bhh, uint2* __restrict__ G1q)
{
  __shared__ __align__(16) _Float16 xs[128*72];    // x k-slab; reused for z
  __shared__ __align__(16) _Float16 wt[128*72];    // weight k-slab
  __shared__ __align__(16) _Float16 act[128*136];  // activations (in place)
  const _Float16* W1h  = w16 + W1_OFF;
  const _Float16* W2h  = w16 + W2_OFF;
  const _Float16* W3h  = w16 + W3_OFF;
  const _Float16* Wihh = w16 + WIH_OFF;
  const int tid  = threadIdx.x;                // 0..511
  const int w    = tid >> 6;                   // 0..7
  const int lane = tid & 63;
  const int ln   = lane & 15;
  const int quad = lane >> 4;
  const int rA   = 16*w + ln;                  // 0..127
  const int r0   = 16*w + quad*4;
  const int R0   = blockIdx.x * 128;
  f32x4 acc[8];

  // ---- layer 1: 256 -> 128, tanh (4 k-slabs of 64) ----
#pragma unroll
  for (int oc = 0; oc < 8; ++oc) acc[oc] = (f32x4)0.f;
  for (int kt = 0; kt < 4; ++kt) {
#pragma unroll
    for (int it = 0; it < 2; ++it) {           // stage x slab [128][64] -> fp16
      int idx = tid + it*512;
      int r = idx >> 3, g8 = idx & 7;
      const float* xp = &x[(size_t)(R0 + r)*OBS + kt*64 + g8*8];
      float4 v0 = *(const float4*)xp;
      float4 v1 = *(const float4*)(xp + 4);
      half8v hv = { (_Float16)v0.x, (_Float16)v0.y, (_Float16)v0.z, (_Float16)v0.w,
                    (_Float16)v1.x, (_Float16)v1.y, (_Float16)v1.z, (_Float16)v1.w };
      *(half8v*)&xs[r*72 + g8*8] = hv;
    }
    stage_wh<128, 256>(W1h, kt*64, wt, tid);
    __syncthreads();
    mfma_slab<8, 72>(xs, wt, rA, ln, quad, acc);
    __syncthreads();
  }
#pragma unroll
  for (int oc = 0; oc < 8; ++oc) {
    int o = oc*16 + ln;
    float bv = b1[o];
#pragma unroll
    for (int r = 0; r < 4; ++r)
      act[(r0 + r)*136 + o] = (_Float16)fast_tanh(acc[oc][r] + bv);
  }

  // ---- layer 2: 128 -> 128, tanh ----
#pragma unroll
  for (int oc = 0; oc < 8; ++oc) acc[oc] = (f32x4)0.f;
  for (int kt = 0; kt < 2; ++kt) {
    stage_wh<128, 128>(W2h, kt*64, wt, tid);
    __syncthreads();                            // publishes act writes + wt
    mfma_slab<8, 136>(act + kt*64, wt, rA, ln, quad, acc);
    __syncthreads();
  }
#pragma unroll
  for (int oc = 0; oc < 8; ++oc) {
    int o = oc*16 + ln;
    float bv = b2[o];
#pragma unroll
    for (int r = 0; r < 4; ++r)
      act[(r0 + r)*136 + o] = (_Float16)fast_tanh(acc[oc][r] + bv);
  }

  // ---- layer 3: 128 -> 64, linear -> z into xs buffer ----
#pragma unroll
  for (int oc = 0; oc < 4; ++oc) acc[oc] = (f32x4)0.f;
  for (int kt = 0; kt < 2; ++kt) {
    stage_wh<64, 128>(W3h, kt*64, wt, tid);
    __syncthreads();
    mfma_slab<4, 136>(act + kt*64, wt, rA, ln, quad, acc);
    __syncthreads();
  }
#pragma unroll
  for (int oc = 0; oc < 4; ++oc) {
    int o = oc*16 + ln;
    float bv = b3[o];
#pragma unroll
    for (int r = 0; r < 4; ++r)
      xs[(r0 + r)*72 + o] = (_Float16)(acc[oc][r] + bv);
  }

  // ---- layer 4: z(64) -> 128 gate inputs, all 4 gates of unit u packed ----
#pragma unroll
  for (int oc = 0; oc < 8; ++oc) acc[oc] = (f32x4)0.f;
  stage_wh<128, 64>(Wihh, 0, wt, tid);
  __syncthreads();                              // publishes z writes + wt
  mfma_slab<8, 72>(xs, wt, rA, ln, quad, acc);
#pragma unroll
  for (int p = 0; p < 2; ++p) {
    int ui = p*16 + ln;
    float bi = bih[ui]      + bhh[ui];
    float bf = bih[ui + 32] + bhh[ui + 32];
    float bg = bih[ui + 64] + bhh[ui + 64];
    float bo = bih[ui + 96] + bhh[ui + 96];
#pragma unroll
    for (int r = 0; r < 4; ++r) {
      int n = R0 + r0 + r;
      uint2 q;
      q.x = h2bits(__builtin_amdgcn_cvt_pkrtz(acc[p  ][r] + bi, acc[p+4][r] + bg));
      q.y = h2bits(__builtin_amdgcn_cvt_pkrtz(acc[p+2][r] + bf, acc[p+6][r] + bo));
      G1q[(size_t)n*32 + ui] = q;
    }
  }
}

// ---------------------------------------------------------------------------
// LSTM scan v10: gate-split wave. Lanes 0-31 compute gates (i,g) for unit u,
// lanes 32-63 compute (f,o) for the same unit (the old layout had the upper
// half doing 100% redundant work). Halves dot2 issue (64 -> 32/step), halves
// Whh register footprint (64 -> 32 VGPR), per-lane G1 load 8B -> 4B, and the
// freed registers fund a 16-deep load pipeline (was 8). One f32 shfl_xor(32)
// pair recombines the four activations; math per value is bit-identical to
// v9 (same formulas, f32 exchange), so accuracy is unchanged.
// ---------------------------------------------------------------------------
__global__ __launch_bounds__(64) void lstm_kernel(
    const uint2* __restrict__ G1q, const float* __restrict__ Whh,
    const int* __restrict__ done, const float* __restrict__ h0,
    const float* __restrict__ c0, unsigned* __restrict__ Y16)
{
  const int lane = threadIdx.x;        // 0..63
  const int u    = lane & 31;
  const int half = lane >> 5;          // 0: (i,g)  1: (f,o)
  const int row  = blockIdx.x;         // 0..511
  const int b    = row >> 5;

  // Whh rows: gate A = i (lo) / f (hi) = u + 32*half ; gate B = g/o = +64
  pk16x2 wA[16], wB[16];
  const int rwA = u + half*32;
#pragma unroll
  for (int k4 = 0; k4 < 8; ++k4) {
    float4 a  = *(const float4*)&Whh[(rwA     )*HID + k4*4];
    float4 bq = *(const float4*)&Whh[(rwA + 64)*HID + k4*4];
    wA[2*k4+0] = __builtin_amdgcn_cvt_pkrtz(a.x,  a.y);
    wA[2*k4+1] = __builtin_amdgcn_cvt_pkrtz(a.z,  a.w);
    wB[2*k4+0] = __builtin_amdgcn_cvt_pkrtz(bq.x, bq.y);
    wB[2*k4+1] = __builtin_amdgcn_cvt_pkrtz(bq.z, bq.w);
  }

  // done -> two 64-bit wave-uniform SGPR masks (bit t = done[t,b] != 0)
  unsigned long long dm0 = __ballot(done[lane*Bn + b] != 0);          // t = 0..63
  unsigned long long dm1 = __ballot(done[(lane + 64)*Bn + b] != 0);   // t = 64..127

  float c = c0[row*HID + u];
  float h = h0[row*HID + u];
  unsigned pk = h2bits(__builtin_amdgcn_cvt_pkrtz(h, dpp_swap1(h)));

  // per-half second-activation constants: lo -> tanh(x)=2*sig(2x)-1, hi -> sig(x)
  const float sSc = half ? 1.f : 2.f;
  const float m1c = half ? 1.f : 2.f;
  const float m0c = half ? 0.f : -1.f;

  // per-lane 4B gate word: lo lanes read q.x=(i,g), hi lanes read q.y=(f,o)
  const unsigned* gb = (const unsigned*)G1q + ((size_t)row*32 + u)*2 + half;
  const size_t gstride = (size_t)BA * 64;        // uints per step
  unsigned q0  = gb[ 0*gstride];
  unsigned q1  = gb[ 1*gstride];
  unsigned q2  = gb[ 2*gstride];
  unsigned q3  = gb[ 3*gstride];
  unsigned q4  = gb[ 4*gstride];
  unsigned q5  = gb[ 5*gstride];
  unsigned q6  = gb[ 6*gstride];
  unsigned q7  = gb[ 7*gstride];
  unsigned q8  = gb[ 8*gstride];
  unsigned q9  = gb[ 9*gstride];
  unsigned q10 = gb[10*gstride];
  unsigned q11 = gb[11*gstride];
  unsigned q12 = gb[12*gstride];
  unsigned q13 = gb[13*gstride];
  unsigned q14 = gb[14*gstride];
  unsigned q15 = gb[15*gstride];

#define LSTM_PHASE(TT, Q)                                                \
  {                                                                      \
    unsigned cur = Q;                                                    \
    int tnx = (TT) + 16; tnx = (tnx < Tn) ? tnx : (Tn - 1);              \
    Q = gb[(size_t)tnx * gstride];                                       \
    unsigned long long dbit = ((TT) < 64) ? (dm0 >> (TT))                \
                                          : (dm1 >> ((TT) - 64));        \
    float m = (dbit & 1ull) ? 0.f : 1.f;   /* scalar-pipe select */      \
    unsigned hp[16];                                                     \
    _Pragma("unroll") for (int k = 0; k < 16; ++k)                       \
      hp[k] = __builtin_amdgcn_readlane(pk, 2*k);                        \
    float aA0=0.f, aA1=0.f, aB0=0.f, aB1=0.f;                            \
    _Pragma("unroll") for (int k = 0; k < 16; k += 2) {                  \
      pk16x2 ha = bits2h(hp[k]), hb = bits2h(hp[k+1]);                   \
      aA0 = dot2(wA[k], ha, aA0); aA1 = dot2(wA[k+1], hb, aA1);          \
      aB0 = dot2(wB[k], ha, aB0); aB1 = dot2(wB[k+1], hb, aB1);          \
    }                                                                    \
    pk16x2 g2 = bits2h(cur);                                             \
    float x0 = fmaf(m, aA0 + aA1, (float)g2.x);   /* i | f */            \
    float x1 = fmaf(m, aB0 + aB1, (float)g2.y);   /* g | o */            \
    float v0 = fast_sig(x0);                                             \
    float v1 = fmaf(m1c, fast_sig(sSc * x1), m0c);                       \
    float o0 = __shfl_xor(v0, 32, 64);                                   \
    float o1 = __shfl_xor(v1, 32, 64);                                   \
    float iv = half ? o0 : v0;                                           \
    float fv = half ? v0 : o0;                                           \
    float gv = half ? o1 : v1;                                           \
    float ov = half ? v1 : o1;                                           \
    c = fmaf(fv, m * c, iv * gv);                                        \
    h = ov * fast_tanh(c);                                               \
    pk = h2bits(__builtin_amdgcn_cvt_pkrtz(h, dpp_swap1(h)));            \
    if ((lane & 33) == 0)                                                \
      Y16[((size_t)(TT)*BA + row)*16 + (u >> 1)] = pk;                   \
  }

  for (int t = 0; t < Tn; t += 16) {
    LSTM_PHASE(t +  0, q0)
    LSTM_PHASE(t +  1, q1)
    LSTM_PHASE(t +  2, q2)
    LSTM_PHASE(t +  3, q3)
    LSTM_PHASE(t +  4, q4)
    LSTM_PHASE(t +  5, q5)
    LSTM_PHASE(t +  6, q6)
    LSTM_PHASE(t +  7, q7)
    LSTM_PHASE(t +  8, q8)
    LSTM_PHASE(t +  9, q9)
    LSTM_PHASE(t + 10, q10)
    LSTM_PHASE(t + 11, q11)
    LSTM_PHASE(t + 12, q12)
    LSTM_PHASE(t + 13, q13)
    LSTM_PHASE(t + 14, q14)
    LSTM_PHASE(t + 15, q15)
  }
#undef LSTM_PHASE
}

// ---------------------------------------------------------------------------
// Heads: per row, 27 logits (3 heads x 9), log-softmax, entropy, gather,
// product of chosen log-probs. One thread per row; Y (fp16 pairs) read
// directly from global.
// ---------------------------------------------------------------------------
__global__ __launch_bounds__(256) void head_kernel(
    const unsigned* __restrict__ Y16, const float* __restrict__ Wh,
    const float* __restrict__ bh, const int* __restrict__ actions,
    float* __restrict__ out)
{
  __shared__ __align__(16) float whs[27*32];
  __shared__ float bhs[32];
  const int tid = threadIdx.x;
  const int R0 = blockIdx.x * 256;
  for (int i = tid; i < 27*32; i += 256) whs[i] = Wh[i];
  if (tid < 27) bhs[tid] = bh[tid];
  const int row = R0 + tid;
  float yv[32];
#pragma unroll
  for (int i4 = 0; i4 < 4; ++i4) {
    uint4 yw = *(const uint4*)&Y16[(size_t)row*16 + i4*4];
    pk16x2 p0 = bits2h(yw.x), p1 = bits2h(yw.y), p2 = bits2h(yw.z), p3 = bits2h(yw.w);
    yv[i4*8+0] = (float)p0.x; yv[i4*8+1] = (float)p0.y;
    yv[i4*8+2] = (float)p1.x; yv[i4*8+3] = (float)p1.y;
    yv[i4*8+4] = (float)p2.x; yv[i4*8+5] = (float)p2.y;
    yv[i4*8+6] = (float)p3.x; yv[i4*8+7] = (float)p3.y;
  }
  __syncthreads();
  float l[27];
#pragma unroll
  for (int m = 0; m < 27; ++m) {
    float a = bhs[m];
#pragma unroll
    for (int k4 = 0; k4 < 8; ++k4) {
      float4 w4 = *(const float4*)&whs[m*32 + k4*4];   // uniform -> broadcast
      a = fmaf(yv[k4*4+0], w4.x, a);
      a = fmaf(yv[k4*4+1], w4.y, a);
      a = fmaf(yv[k4*4+2], w4.z, a);
      a = fmaf(yv[k4*4+3], w4.w, a);
    }
    l[m] = a;
  }
  float logprob = 1.0f;
#pragma unroll
  for (int kk = 0; kk < 3; ++kk) {
    float mx = l[kk*9];
#pragma unroll
    for (int n = 1; n < 9; ++n) mx = fmaxf(mx, l[kk*9+n]);
    float s = 0.f;
#pragma unroll
    for (int n = 0; n < 9; ++n) s += __expf(l[kk*9+n] - mx);
    float lse = mx + __logf(s);
    float ent = 0.f;
#pragma unroll
    for (int n = 0; n < 9; ++n) {
      float lp = l[kk*9+n] - lse;
      ent -= __expf(lp) * lp;
    }
    int a = actions[row*3 + kk];
    float alp = 0.f;
#pragma unroll
    for (int n = 0; n < 9; ++n) alp = (a == n) ? (l[kk*9+n] - lse) : alp;
    logprob *= alp;
    out[OUT_ENT + row*3 + kk] = ent;     // actions echoed by cvtw_act_kernel
  }
  out[OUT_LP + row] = logprob;
}

extern "C" void kernel_launch(void* const* d_in, const int* in_sizes, int n_in,
                              void* d_out, int out_size, void* d_ws, size_t ws_size,
                              hipStream_t stream)
{
  const float* x       = (const float*)d_in[0];
  const int*   done    = (const int*)  d_in[1];
  const int*   actions = (const int*)  d_in[2];
  const float* W1  = (const float*)d_in[3];
  const float* b1  = (const float*)d_in[4];
  const float* W2  = (const float*)d_in[5];
  const float* b2  = (const float*)d_in[6];
  const float* W3  = (const float*)d_in[7];
  const float* b3  = (const float*)d_in[8];
  const float* Wih = (const float*)d_in[9];
  const float* Whh = (const float*)d_in[10];
  const float* bih = (const float*)d_in[11];
  const float* bhh = (const float*)d_in[12];
  const float* Wh  = (const float*)d_in[13];
  const float* bh  = (const float*)d_in[14];
  const float* h0  = (const float*)d_in[15];
  const float* c0  = (const float*)d_in[16];
  float* out = (float*)d_out;

  uint2* G1q = (uint2*)d_ws;                         // TBA*32 uint2 = 16.8 MB
  unsigned* Y16 = (unsigned*)(G1q + (size_t)TBA*32); // TBA*16 uints =  4.2 MB
  _Float16* W16 = (_Float16*)(Y16 + (size_t)TBA*16); // 128 KB

  cvtw_act_kernel<<<W16_TOT/256 + (TBA*Kh)/256, 256, 0, stream>>>(
      W1, W2, W3, Wih, W16, actions, out);
  mlp_kernel<<<TBA/128, 512, 0, stream>>>(x, W16, b1, b2, b3, bih, bhh, G1q);
  lstm_kernel<<<BA, 64, 0, stream>>>(G1q, Whh, done, h0, c0, Y16);
  head_kernel<<<TBA/256, 256, 0, stream>>>(Y16, Wh, bh, actions, out);
}

// Round 2
// 172.419 us; speedup vs baseline: 1.1270x; 1.0850x over previous
//
#include <hip/hip_runtime.h>
#include <math.h>

namespace {
constexpr int Tn = 128, Bn = 16, An = 32, OBS = 256, Kh = 3, NACT = 9, HID = 32;
constexpr int TBA = Tn * Bn * An;   // 65536 rows through the MLP
constexpr int BA  = Bn * An;        // 512 LSTM sequences
constexpr int OUT_LP  = TBA * Kh;         // 196608: logprobs start
constexpr int OUT_ENT = TBA * Kh + TBA;   // 262144: entropies start
constexpr int NCHUNK = 8;                 // time-chunks per row (done-reset cuts)
constexpr int CHUNKW = Tn / NCHUNK;       // nominal chunk width (16)

// fp16 weight pack offsets (elements)
constexpr int W1_OFF  = 0;       // 128x256
constexpr int W2_OFF  = 32768;   // 128x128
constexpr int W3_OFF  = 49152;   // 64x128
constexpr int WIH_OFF = 57344;   // 128x64
constexpr int W16_TOT = 65536;

typedef __fp16   pk16x2 __attribute__((ext_vector_type(2)));  // builtin-compatible
typedef _Float16 half8v __attribute__((ext_vector_type(8)));
typedef float    f32x4  __attribute__((ext_vector_type(4)));
}

__device__ __forceinline__ float fast_sig(float x) {
  return __builtin_amdgcn_rcpf(1.f + __expf(-x));
}
__device__ __forceinline__ float fast_tanh(float x) {   // 2*sig(2x)-1, saturates safely
  return fmaf(2.f, fast_sig(2.f * x), -1.f);
}
__device__ __forceinline__ unsigned h2bits(pk16x2 h) {
  return __builtin_bit_cast(unsigned, h);
}
__device__ __forceinline__ pk16x2 bits2h(unsigned u) {
  return __builtin_bit_cast(pk16x2, u);
}
__device__ __forceinline__ float dot2(pk16x2 a, pk16x2 b, float c) {
#if __has_builtin(__builtin_amdgcn_fdot2)
  return __builtin_amdgcn_fdot2(a, b, c, false);
#else
  c = fmaf((float)a.x, (float)b.x, c);
  return fmaf((float)a.y, (float)b.y, c);
#endif
}
// swap adjacent lanes (xor 1) via DPP quad_perm(1,0,3,2): VALU, no DS pipe
__device__ __forceinline__ float dpp_swap1(float x) {
  return __uint_as_float((unsigned)__builtin_amdgcn_mov_dpp(
      (int)__float_as_uint(x), 0xB1, 0xF, 0xF, true));
}
// first set bit index >= n in the 128-bit mask {dm0, dm1}; 128 if none.
// n is wave-uniform. Used to find done-reset chunk boundaries.
__device__ __forceinline__ int first_done_ge(unsigned long long dm0,
                                             unsigned long long dm1, int n) {
  unsigned long long m0 = (n < 64) ? (dm0 & (~0ull << n)) : 0ull;
  unsigned long long m1 = (n < 64) ? dm1 : (dm1 & (~0ull << (n - 64)));
  if (m0) return __builtin_ctzll(m0);
  if (m1) return 64 + __builtin_ctzll(m1);
  return 128;
}

// ---------------------------------------------------------------------------
// Weight fp32->fp16 pre-conversion + actions echo (fused, one launch).
// ---------------------------------------------------------------------------
__global__ __launch_bounds__(256) void cvtw_act_kernel(
    const float* __restrict__ W1, const float* __restrict__ W2,
    const float* __restrict__ W3, const float* __restrict__ Wih,
    _Float16* __restrict__ w16, const int* __restrict__ actions,
    float* __restrict__ out)
{
  const int bid = blockIdx.x;
  if (bid < W16_TOT/256) {
    int i = bid * 256 + threadIdx.x;            // 0..65535
    float v;
    if (i < W2_OFF)       v = W1[i];
    else if (i < W3_OFF)  v = W2[i - W2_OFF];
    else if (i < WIH_OFF) v = W3[i - W3_OFF];
    else                  v = Wih[i - WIH_OFF];
    w16[i] = (_Float16)v;
  } else {
    int i = (bid - W16_TOT/256) * 256 + threadIdx.x;  // 0..196607
    out[i] = (float)actions[i];
  }
}

// ---------------------------------------------------------------------------
// Fused MLP trunk + LSTM input projection, f16 MFMA (fp32 accumulate).
// v3: 512 threads (8 waves), 128 rows/block, 512 blocks -> halves per-row
// weight-staging traffic and barrier count. LDS 71.7 KB -> 2 blocks/CU.
// ---------------------------------------------------------------------------
template<int ROWS, int WSTR>
__device__ __forceinline__ void stage_wh(const _Float16* __restrict__ Wg, int kofs,
                                         _Float16* __restrict__ wt, int tid)
{
#pragma unroll
  for (int it = 0; it < ROWS/64; ++it) {        // ROWS*8 units / 512 threads
    int idx = tid + it*512;
    int o = idx >> 3, g8 = idx & 7;
    *(half8v*)&wt[o*72 + g8*8] =
        *(const half8v*)&Wg[(size_t)o*WSTR + kofs + g8*8];
  }
}

template<int NOC, int XSTR>
__device__ __forceinline__ void mfma_slab(const _Float16* __restrict__ xsrc,
                                          const _Float16* __restrict__ wt,
                                          int rA, int ln, int quad, f32x4 acc[8])
{
#pragma unroll
  for (int kc = 0; kc < 2; ++kc) {
    half8v a = *(const half8v*)&xsrc[rA*XSTR + kc*32 + quad*8];
#pragma unroll
    for (int oc = 0; oc < NOC; ++oc) {
      half8v b = *(const half8v*)&wt[(oc*16 + ln)*72 + kc*32 + quad*8];
      acc[oc] = __builtin_amdgcn_mfma_f32_16x16x32_f16(a, b, acc[oc], 0, 0, 0);
    }
  }
}

__global__ __launch_bounds__(512) void mlp_kernel(
    const float* __restrict__ x, const _Float16* __restrict__ w16,
    const float* __restrict__ b1, const float* __restrict__ b2,
    const float* __restrict__ b3, const float* __restrict__ bih,
    const float* __restrict__ bhh, uint2* __restrict__ G1q)
{
  __shared__ __align__(16) _Float16 xs[128*72];    // x k-slab; reused for z
  __shared__ __align__(16) _Float16 wt[128*72];    // weight k-slab
  __shared__ __align__(16) _Float16 act[128*136];  // activations (in place)
  const _Float16* W1h  = w16 + W1_OFF;
  const _Float16* W2h  = w16 + W2_OFF;
  const _Float16* W3h  = w16 + W3_OFF;
  const _Float16* Wihh = w16 + WIH_OFF;
  const int tid  = threadIdx.x;                // 0..511
  const int w    = tid >> 6;                   // 0..7
  const int lane = tid & 63;
  const int ln   = lane & 15;
  const int quad = lane >> 4;
  const int rA   = 16*w + ln;                  // 0..127
  const int r0   = 16*w + quad*4;
  const int R0   = blockIdx.x * 128;
  f32x4 acc[8];

  // ---- layer 1: 256 -> 128, tanh (4 k-slabs of 64) ----
#pragma unroll
  for (int oc = 0; oc < 8; ++oc) acc[oc] = (f32x4)0.f;
  for (int kt = 0; kt < 4; ++kt) {
#pragma unroll
    for (int it = 0; it < 2; ++it) {           // stage x slab [128][64] -> fp16
      int idx = tid + it*512;
      int r = idx >> 3, g8 = idx & 7;
      const float* xp = &x[(size_t)(R0 + r)*OBS + kt*64 + g8*8];
      float4 v0 = *(const float4*)xp;
      float4 v1 = *(const float4*)(xp + 4);
      half8v hv = { (_Float16)v0.x, (_Float16)v0.y, (_Float16)v0.z, (_Float16)v0.w,
                    (_Float16)v1.x, (_Float16)v1.y, (_Float16)v1.z, (_Float16)v1.w };
      *(half8v*)&xs[r*72 + g8*8] = hv;
    }
    stage_wh<128, 256>(W1h, kt*64, wt, tid);
    __syncthreads();
    mfma_slab<8, 72>(xs, wt, rA, ln, quad, acc);
    __syncthreads();
  }
#pragma unroll
  for (int oc = 0; oc < 8; ++oc) {
    int o = oc*16 + ln;
    float bv = b1[o];
#pragma unroll
    for (int r = 0; r < 4; ++r)
      act[(r0 + r)*136 + o] = (_Float16)fast_tanh(acc[oc][r] + bv);
  }

  // ---- layer 2: 128 -> 128, tanh ----
#pragma unroll
  for (int oc = 0; oc < 8; ++oc) acc[oc] = (f32x4)0.f;
  for (int kt = 0; kt < 2; ++kt) {
    stage_wh<128, 128>(W2h, kt*64, wt, tid);
    __syncthreads();                            // publishes act writes + wt
    mfma_slab<8, 136>(act + kt*64, wt, rA, ln, quad, acc);
    __syncthreads();
  }
#pragma unroll
  for (int oc = 0; oc < 8; ++oc) {
    int o = oc*16 + ln;
    float bv = b2[o];
#pragma unroll
    for (int r = 0; r < 4; ++r)
      act[(r0 + r)*136 + o] = (_Float16)fast_tanh(acc[oc][r] + bv);
  }

  // ---- layer 3: 128 -> 64, linear -> z into xs buffer ----
#pragma unroll
  for (int oc = 0; oc < 4; ++oc) acc[oc] = (f32x4)0.f;
  for (int kt = 0; kt < 2; ++kt) {
    stage_wh<64, 128>(W3h, kt*64, wt, tid);
    __syncthreads();
    mfma_slab<4, 136>(act + kt*64, wt, rA, ln, quad, acc);
    __syncthreads();
  }
#pragma unroll
  for (int oc = 0; oc < 4; ++oc) {
    int o = oc*16 + ln;
    float bv = b3[o];
#pragma unroll
    for (int r = 0; r < 4; ++r)
      xs[(r0 + r)*72 + o] = (_Float16)(acc[oc][r] + bv);
  }

  // ---- layer 4: z(64) -> 128 gate inputs, all 4 gates of unit u packed ----
#pragma unroll
  for (int oc = 0; oc < 8; ++oc) acc[oc] = (f32x4)0.f;
  stage_wh<128, 64>(Wihh, 0, wt, tid);
  __syncthreads();                              // publishes z writes + wt
  mfma_slab<8, 72>(xs, wt, rA, ln, quad, acc);
#pragma unroll
  for (int p = 0; p < 2; ++p) {
    int ui = p*16 + ln;
    float bi = bih[ui]      + bhh[ui];
    float bf = bih[ui + 32] + bhh[ui + 32];
    float bg = bih[ui + 64] + bhh[ui + 64];
    float bo = bih[ui + 96] + bhh[ui + 96];
#pragma unroll
    for (int r = 0; r < 4; ++r) {
      int n = R0 + r0 + r;
      uint2 q;
      q.x = h2bits(__builtin_amdgcn_cvt_pkrtz(acc[p  ][r] + bi, acc[p+4][r] + bg));
      q.y = h2bits(__builtin_amdgcn_cvt_pkrtz(acc[p+2][r] + bf, acc[p+6][r] + bo));
      G1q[(size_t)n*32 + ui] = q;
    }
  }
}

// ---------------------------------------------------------------------------
// LSTM scan v11: done-reset time-chunking. done[t,b]=1 zeroes h,c BEFORE
// step t, so every done position is a hard reset with known state (0,0).
// Each row's 128 steps are cut into NCHUNK=8 chunks; chunk k starts at the
// first done >= 16k (chunk 0 starts at t=0 with h0,c0). Chunks are fully
// independent -> 4096 waves (4/SIMD) instead of 512, and the serial chain
// per wave drops from 128 steps to ~16-26. Same step math as v10
// (gate-split wave: lanes 0-31 compute (i,g), lanes 32-63 (f,o)).
// ---------------------------------------------------------------------------
__global__ __launch_bounds__(64) void lstm_kernel(
    const uint2* __restrict__ G1q, const float* __restrict__ Whh,
    const int* __restrict__ done, const float* __restrict__ h0,
    const float* __restrict__ c0, unsigned* __restrict__ Y16)
{
  static_assert(BA == 512 && NCHUNK == 8, "index math below assumes 512x8");
  const int lane = threadIdx.x;        // 0..63
  const int u    = lane & 31;
  const int half = lane >> 5;          // 0: (i,g)  1: (f,o)
  const int row  = blockIdx.x & (BA - 1);   // 0..511
  const int ck   = blockIdx.x >> 9;         // 0..7 chunk index
  const int b    = row >> 5;

  // done -> two 64-bit wave-uniform SGPR masks (bit t = done[t,b] != 0)
  unsigned long long dm0 = __ballot(done[lane*Bn + b] != 0);          // t = 0..63
  unsigned long long dm1 = __ballot(done[(lane + 64)*Bn + b] != 0);   // t = 64..127

  // chunk bounds: [s, e). s is a done-reset (or t=0), so state at s is known.
  const int s = (ck == 0) ? 0 : first_done_ge(dm0, dm1, ck * CHUNKW);
  const int e = (ck == NCHUNK - 1) ? Tn
                                   : first_done_ge(dm0, dm1, (ck + 1) * CHUNKW);
  if (s >= e) return;                  // empty chunk

  // Whh rows: gate A = i (lo) / f (hi) = u + 32*half ; gate B = g/o = +64
  pk16x2 wA[16], wB[16];
  const int rwA = u + half*32;
#pragma unroll
  for (int k4 = 0; k4 < 8; ++k4) {
    float4 a  = *(const float4*)&Whh[(rwA     )*HID + k4*4];
    float4 bq = *(const float4*)&Whh[(rwA + 64)*HID + k4*4];
    wA[2*k4+0] = __builtin_amdgcn_cvt_pkrtz(a.x,  a.y);
    wA[2*k4+1] = __builtin_amdgcn_cvt_pkrtz(a.z,  a.w);
    wB[2*k4+0] = __builtin_amdgcn_cvt_pkrtz(bq.x, bq.y);
    wB[2*k4+1] = __builtin_amdgcn_cvt_pkrtz(bq.z, bq.w);
  }

  // initial state: h0/c0 only for the t=0 chunk; other chunks start at a
  // done-reset, where the step itself zero-masks history (h=c=0 consistent).
  float c, h;
  if (ck == 0) { c = c0[row*HID + u]; h = h0[row*HID + u]; }
  else         { c = 0.f;             h = 0.f; }
  unsigned pk = h2bits(__builtin_amdgcn_cvt_pkrtz(h, dpp_swap1(h)));

  // per-half second-activation constants: lo -> tanh(x)=2*sig(2x)-1, hi -> sig(x)
  const float sSc = half ? 1.f : 2.f;
  const float m1c = half ? 1.f : 2.f;
  const float m0c = half ? 0.f : -1.f;

  // per-lane 4B gate word: lo lanes read q.x=(i,g), hi lanes read q.y=(f,o)
  const unsigned* gb = (const unsigned*)G1q + ((size_t)row*32 + u)*2 + half;
  const size_t gstride = (size_t)BA * 64;        // uints per step

  unsigned qcur = gb[(size_t)s * gstride];
  for (int t = s; t < e; ++t) {
    int tn = t + 1; tn = (tn < e) ? tn : (e - 1);
    unsigned qnext = gb[(size_t)tn * gstride];   // depth-1 prefetch; TLP hides rest

    unsigned long long dbit = (t < 64) ? (dm0 >> t) : (dm1 >> (t - 64));
    float m = (dbit & 1ull) ? 0.f : 1.f;         // scalar-pipe select
    unsigned hp[16];
#pragma unroll
    for (int k = 0; k < 16; ++k)
      hp[k] = __builtin_amdgcn_readlane(pk, 2*k);
    float aA0 = 0.f, aA1 = 0.f, aB0 = 0.f, aB1 = 0.f;
#pragma unroll
    for (int k = 0; k < 16; k += 2) {
      pk16x2 ha = bits2h(hp[k]), hb = bits2h(hp[k+1]);
      aA0 = dot2(wA[k], ha, aA0); aA1 = dot2(wA[k+1], hb, aA1);
      aB0 = dot2(wB[k], ha, aB0); aB1 = dot2(wB[k+1], hb, aB1);
    }
    pk16x2 g2 = bits2h(qcur);
    float x0 = fmaf(m, aA0 + aA1, (float)g2.x);  // i | f
    float x1 = fmaf(m, aB0 + aB1, (float)g2.y);  // g | o
    float v0 = fast_sig(x0);
    float v1 = fmaf(m1c, fast_sig(sSc * x1), m0c);
    float o0 = __shfl_xor(v0, 32, 64);
    float o1 = __shfl_xor(v1, 32, 64);
    float iv = half ? o0 : v0;
    float fv = half ? v0 : o0;
    float gv = half ? o1 : v1;
    float ov = half ? v1 : o1;
    c = fmaf(fv, m * c, iv * gv);
    h = ov * fast_tanh(c);
    pk = h2bits(__builtin_amdgcn_cvt_pkrtz(h, dpp_swap1(h)));
    if ((lane & 33) == 0)
      Y16[((size_t)t*BA + row)*16 + (u >> 1)] = pk;

    qcur = qnext;
  }
}

// ---------------------------------------------------------------------------
// Heads: per row, 27 logits (3 heads x 9), log-softmax, entropy, gather,
// product of chosen log-probs. One thread per row; Y (fp16 pairs) read
// directly from global.
// ---------------------------------------------------------------------------
__global__ __launch_bounds__(256) void head_kernel(
    const unsigned* __restrict__ Y16, const float* __restrict__ Wh,
    const float* __restrict__ bh, const int* __restrict__ actions,
    float* __restrict__ out)
{
  __shared__ __align__(16) float whs[27*32];
  __shared__ float bhs[32];
  const int tid = threadIdx.x;
  const int R0 = blockIdx.x * 256;
  for (int i = tid; i < 27*32; i += 256) whs[i] = Wh[i];
  if (tid < 27) bhs[tid] = bh[tid];
  const int row = R0 + tid;
  float yv[32];
#pragma unroll
  for (int i4 = 0; i4 < 4; ++i4) {
    uint4 yw = *(const uint4*)&Y16[(size_t)row*16 + i4*4];
    pk16x2 p0 = bits2h(yw.x), p1 = bits2h(yw.y), p2 = bits2h(yw.z), p3 = bits2h(yw.w);
    yv[i4*8+0] = (float)p0.x; yv[i4*8+1] = (float)p0.y;
    yv[i4*8+2] = (float)p1.x; yv[i4*8+3] = (float)p1.y;
    yv[i4*8+4] = (float)p2.x; yv[i4*8+5] = (float)p2.y;
    yv[i4*8+6] = (float)p3.x; yv[i4*8+7] = (float)p3.y;
  }
  __syncthreads();
  float l[27];
#pragma unroll
  for (int m = 0; m < 27; ++m) {
    float a = bhs[m];
#pragma unroll
    for (int k4 = 0; k4 < 8; ++k4) {
      float4 w4 = *(const float4*)&whs[m*32 + k4*4];   // uniform -> broadcast
      a = fmaf(yv[k4*4+0], w4.x, a);
      a = fmaf(yv[k4*4+1], w4.y, a);
      a = fmaf(yv[k4*4+2], w4.z, a);
      a = fmaf(yv[k4*4+3], w4.w, a);
    }
    l[m] = a;
  }
  float logprob = 1.0f;
#pragma unroll
  for (int kk = 0; kk < 3; ++kk) {
    float mx = l[kk*9];
#pragma unroll
    for (int n = 1; n < 9; ++n) mx = fmaxf(mx, l[kk*9+n]);
    float s = 0.f;
#pragma unroll
    for (int n = 0; n < 9; ++n) s += __expf(l[kk*9+n] - mx);
    float lse = mx + __logf(s);
    float ent = 0.f;
#pragma unroll
    for (int n = 0; n < 9; ++n) {
      float lp = l[kk*9+n] - lse;
      ent -= __expf(lp) * lp;
    }
    int a = actions[row*3 + kk];
    float alp = 0.f;
#pragma unroll
    for (int n = 0; n < 9; ++n) alp = (a == n) ? (l[kk*9+n] - lse) : alp;
    logprob *= alp;
    out[OUT_ENT + row*3 + kk] = ent;     // actions echoed by cvtw_act_kernel
  }
  out[OUT_LP + row] = logprob;
}

extern "C" void kernel_launch(void* const* d_in, const int* in_sizes, int n_in,
                              void* d_out, int out_size, void* d_ws, size_t ws_size,
                              hipStream_t stream)
{
  const float* x       = (const float*)d_in[0];
  const int*   done    = (const int*)  d_in[1];
  const int*   actions = (const int*)  d_in[2];
  const float* W1  = (const float*)d_in[3];
  const float* b1  = (const float*)d_in[4];
  const float* W2  = (const float*)d_in[5];
  const float* b2  = (const float*)d_in[6];
  const float* W3  = (const float*)d_in[7];
  const float* b3  = (const float*)d_in[8];
  const float* Wih = (const float*)d_in[9];
  const float* Whh = (const float*)d_in[10];
  const float* bih = (const float*)d_in[11];
  const float* bhh = (const float*)d_in[12];
  const float* Wh  = (const float*)d_in[13];
  const float* bh  = (const float*)d_in[14];
  const float* h0  = (const float*)d_in[15];
  const float* c0  = (const float*)d_in[16];
  float* out = (float*)d_out;

  uint2* G1q = (uint2*)d_ws;                         // TBA*32 uint2 = 16.8 MB
  unsigned* Y16 = (unsigned*)(G1q + (size_t)TBA*32); // TBA*16 uints =  4.2 MB
  _Float16* W16 = (_Float16*)(Y16 + (size_t)TBA*16); // 128 KB

  cvtw_act_kernel<<<W16_TOT/256 + (TBA*Kh)/256, 256, 0, stream>>>(
      W1, W2, W3, Wih, W16, actions, out);
  mlp_kernel<<<TBA/128, 512, 0, stream>>>(x, W16, b1, b2, b3, bih, bhh, G1q);
  lstm_kernel<<<BA * NCHUNK, 64, 0, stream>>>(G1q, Whh, done, h0, c0, Y16);
  head_kernel<<<TBA/256, 256, 0, stream>>>(Y16, Wh, bh, actions, out);
}

// Round 4
// 171.747 us; speedup vs baseline: 1.1315x; 1.0039x over previous
//
#include <hip/hip_runtime.h>
#include <math.h>

namespace {
constexpr int Tn = 128, Bn = 16, An = 32, OBS = 256, Kh = 3, NACT = 9, HID = 32;
constexpr int TBA = Tn * Bn * An;   // 65536 rows through the MLP
constexpr int BA  = Bn * An;        // 512 LSTM sequences
constexpr int OUT_LP  = TBA * Kh;         // 196608: logprobs start
constexpr int OUT_ENT = TBA * Kh + TBA;   // 262144: entropies start
constexpr int NCHUNK = 16;                // time-chunks per row (done-reset cuts)
constexpr int CHUNKW = Tn / NCHUNK;       // nominal chunk width (8)

// fp16 weight pack offsets (elements)
constexpr int W1_OFF  = 0;       // 128x256
constexpr int W2_OFF  = 32768;   // 128x128
constexpr int W3_OFF  = 49152;   // 64x128
constexpr int WIH_OFF = 57344;   // 128x64
constexpr int W16_TOT = 65536;

typedef __fp16   pk16x2 __attribute__((ext_vector_type(2)));  // builtin-compatible
typedef _Float16 half8v __attribute__((ext_vector_type(8)));
typedef float    f32x4  __attribute__((ext_vector_type(4)));
}

__device__ __forceinline__ float fast_sig(float x) {
  return __builtin_amdgcn_rcpf(1.f + __expf(-x));
}
__device__ __forceinline__ float fast_tanh(float x) {   // 2*sig(2x)-1, saturates safely
  return fmaf(2.f, fast_sig(2.f * x), -1.f);
}
__device__ __forceinline__ unsigned h2bits(pk16x2 h) {
  return __builtin_bit_cast(unsigned, h);
}
__device__ __forceinline__ pk16x2 bits2h(unsigned u) {
  return __builtin_bit_cast(pk16x2, u);
}
__device__ __forceinline__ float dot2(pk16x2 a, pk16x2 b, float c) {
#if __has_builtin(__builtin_amdgcn_fdot2)
  return __builtin_amdgcn_fdot2(a, b, c, false);
#else
  c = fmaf((float)a.x, (float)b.x, c);
  return fmaf((float)a.y, (float)b.y, c);
#endif
}
// swap adjacent lanes (xor 1) via DPP quad_perm(1,0,3,2): VALU, no DS pipe
__device__ __forceinline__ float dpp_swap1(float x) {
  return __uint_as_float((unsigned)__builtin_amdgcn_mov_dpp(
      (int)__float_as_uint(x), 0xB1, 0xF, 0xF, true));
}
// swap lane pairs within quad via DPP quad_perm(2,3,0,1): lane 4m <-> 4m+2 etc.
__device__ __forceinline__ float dpp_quad2(float x) {
  return __uint_as_float((unsigned)__builtin_amdgcn_mov_dpp(
      (int)__float_as_uint(x), 0x4E, 0xF, 0xF, true));
}
// first set bit index >= n in the 128-bit mask {dm0, dm1}; 128 if none.
// n is wave-uniform. Used to find done-reset chunk boundaries.
__device__ __forceinline__ int first_done_ge(unsigned long long dm0,
                                             unsigned long long dm1, int n) {
  unsigned long long m0 = (n < 64) ? (dm0 & (~0ull << n)) : 0ull;
  unsigned long long m1 = (n < 64) ? dm1 : (dm1 & (~0ull << (n - 64)));
  if (m0) return __builtin_ctzll(m0);
  if (m1) return 64 + __builtin_ctzll(m1);
  return 128;
}

// ---------------------------------------------------------------------------
// Weight fp32->fp16 pre-conversion + actions echo (fused, one launch).
// ---------------------------------------------------------------------------
__global__ __launch_bounds__(256) void cvtw_act_kernel(
    const float* __restrict__ W1, const float* __restrict__ W2,
    const float* __restrict__ W3, const float* __restrict__ Wih,
    _Float16* __restrict__ w16, const int* __restrict__ actions,
    float* __restrict__ out)
{
  const int bid = blockIdx.x;
  if (bid < W16_TOT/256) {
    int i = bid * 256 + threadIdx.x;            // 0..65535
    float v;
    if (i < W2_OFF)       v = W1[i];
    else if (i < W3_OFF)  v = W2[i - W2_OFF];
    else if (i < WIH_OFF) v = W3[i - W3_OFF];
    else                  v = Wih[i - WIH_OFF];
    w16[i] = (_Float16)v;
  } else {
    int i = (bid - W16_TOT/256) * 256 + threadIdx.x;  // 0..196607
    out[i] = (float)actions[i];
  }
}

// ---------------------------------------------------------------------------
// Fused MLP trunk + LSTM input projection, f16 MFMA (fp32 accumulate).
// v3: 512 threads (8 waves), 128 rows/block, 512 blocks -> halves per-row
// weight-staging traffic and barrier count. LDS 71.7 KB -> 2 blocks/CU.
// ---------------------------------------------------------------------------
template<int ROWS, int WSTR>
__device__ __forceinline__ void stage_wh(const _Float16* __restrict__ Wg, int kofs,
                                         _Float16* __restrict__ wt, int tid)
{
#pragma unroll
  for (int it = 0; it < ROWS/64; ++it) {        // ROWS*8 units / 512 threads
    int idx = tid + it*512;
    int o = idx >> 3, g8 = idx & 7;
    *(half8v*)&wt[o*72 + g8*8] =
        *(const half8v*)&Wg[(size_t)o*WSTR + kofs + g8*8];
  }
}

template<int NOC, int XSTR>
__device__ __forceinline__ void mfma_slab(const _Float16* __restrict__ xsrc,
                                          const _Float16* __restrict__ wt,
                                          int rA, int ln, int quad, f32x4 acc[8])
{
#pragma unroll
  for (int kc = 0; kc < 2; ++kc) {
    half8v a = *(const half8v*)&xsrc[rA*XSTR + kc*32 + quad*8];
#pragma unroll
    for (int oc = 0; oc < NOC; ++oc) {
      half8v b = *(const half8v*)&wt[(oc*16 + ln)*72 + kc*32 + quad*8];
      acc[oc] = __builtin_amdgcn_mfma_f32_16x16x32_f16(a, b, acc[oc], 0, 0, 0);
    }
  }
}

__global__ __launch_bounds__(512) void mlp_kernel(
    const float* __restrict__ x, const _Float16* __restrict__ w16,
    const float* __restrict__ b1, const float* __restrict__ b2,
    const float* __restrict__ b3, const float* __restrict__ bih,
    const float* __restrict__ bhh, uint2* __restrict__ G1q)
{
  __shared__ __align__(16) _Float16 xs[128*72];    // x k-slab; reused for z
  __shared__ __align__(16) _Float16 wt[128*72];    // weight k-slab
  __shared__ __align__(16) _Float16 act[128*136];  // activations (in place)
  const _Float16* W1h  = w16 + W1_OFF;
  const _Float16* W2h  = w16 + W2_OFF;
  const _Float16* W3h  = w16 + W3_OFF;
  const _Float16* Wihh = w16 + WIH_OFF;
  const int tid  = threadIdx.x;                // 0..511
  const int w    = tid >> 6;                   // 0..7
  const int lane = tid & 63;
  const int ln   = lane & 15;
  const int quad = lane >> 4;
  const int rA   = 16*w + ln;                  // 0..127
  const int r0   = 16*w + quad*4;
  const int R0   = blockIdx.x * 128;
  f32x4 acc[8];

  // ---- layer 1: 256 -> 128, tanh (4 k-slabs of 64) ----
#pragma unroll
  for (int oc = 0; oc < 8; ++oc) acc[oc] = (f32x4)0.f;
  for (int kt = 0; kt < 4; ++kt) {
#pragma unroll
    for (int it = 0; it < 2; ++it) {           // stage x slab [128][64] -> fp16
      int idx = tid + it*512;
      int r = idx >> 3, g8 = idx & 7;
      const float* xp = &x[(size_t)(R0 + r)*OBS + kt*64 + g8*8];
      float4 v0 = *(const float4*)xp;
      float4 v1 = *(const float4*)(xp + 4);
      half8v hv = { (_Float16)v0.x, (_Float16)v0.y, (_Float16)v0.z, (_Float16)v0.w,
                    (_Float16)v1.x, (_Float16)v1.y, (_Float16)v1.z, (_Float16)v1.w };
      *(half8v*)&xs[r*72 + g8*8] = hv;
    }
    stage_wh<128, 256>(W1h, kt*64, wt, tid);
    __syncthreads();
    mfma_slab<8, 72>(xs, wt, rA, ln, quad, acc);
    __syncthreads();
  }
#pragma unroll
  for (int oc = 0; oc < 8; ++oc) {
    int o = oc*16 + ln;
    float bv = b1[o];
#pragma unroll
    for (int r = 0; r < 4; ++r)
      act[(r0 + r)*136 + o] = (_Float16)fast_tanh(acc[oc][r] + bv);
  }

  // ---- layer 2: 128 -> 128, tanh ----
#pragma unroll
  for (int oc = 0; oc < 8; ++oc) acc[oc] = (f32x4)0.f;
  for (int kt = 0; kt < 2; ++kt) {
    stage_wh<128, 128>(W2h, kt*64, wt, tid);
    __syncthreads();                            // publishes act writes + wt
    mfma_slab<8, 136>(act + kt*64, wt, rA, ln, quad, acc);
    __syncthreads();
  }
#pragma unroll
  for (int oc = 0; oc < 8; ++oc) {
    int o = oc*16 + ln;
    float bv = b2[o];
#pragma unroll
    for (int r = 0; r < 4; ++r)
      act[(r0 + r)*136 + o] = (_Float16)fast_tanh(acc[oc][r] + bv);
  }

  // ---- layer 3: 128 -> 64, linear -> z into xs buffer ----
#pragma unroll
  for (int oc = 0; oc < 4; ++oc) acc[oc] = (f32x4)0.f;
  for (int kt = 0; kt < 2; ++kt) {
    stage_wh<64, 128>(W3h, kt*64, wt, tid);
    __syncthreads();
    mfma_slab<4, 136>(act + kt*64, wt, rA, ln, quad, acc);
    __syncthreads();
  }
#pragma unroll
  for (int oc = 0; oc < 4; ++oc) {
    int o = oc*16 + ln;
    float bv = b3[o];
#pragma unroll
    for (int r = 0; r < 4; ++r)
      xs[(r0 + r)*72 + o] = (_Float16)(acc[oc][r] + bv);
  }

  // ---- layer 4: z(64) -> 128 gate inputs, all 4 gates of unit u packed ----
#pragma unroll
  for (int oc = 0; oc < 8; ++oc) acc[oc] = (f32x4)0.f;
  stage_wh<128, 64>(Wihh, 0, wt, tid);
  __syncthreads();                              // publishes z writes + wt
  mfma_slab<8, 72>(xs, wt, rA, ln, quad, acc);
#pragma unroll
  for (int p = 0; p < 2; ++p) {
    int ui = p*16 + ln;
    float bi = bih[ui]      + bhh[ui];
    float bf = bih[ui + 32] + bhh[ui + 32];
    float bg = bih[ui + 64] + bhh[ui + 64];
    float bo = bih[ui + 96] + bhh[ui + 96];
#pragma unroll
    for (int r = 0; r < 4; ++r) {
      int n = R0 + r0 + r;
      uint2 q;
      q.x = h2bits(__builtin_amdgcn_cvt_pkrtz(acc[p  ][r] + bi, acc[p+4][r] + bg));
      q.y = h2bits(__builtin_amdgcn_cvt_pkrtz(acc[p+2][r] + bf, acc[p+6][r] + bo));
      G1q[(size_t)n*32 + ui] = q;
    }
  }
}

// ---------------------------------------------------------------------------
// LSTM scan v12: done-reset chunking (NCHUNK=16) + lane-pair layout.
// lane = 2u + half (half 0 -> gates i,g; half 1 -> f,o). The activation
// exchange partner is lane^1 -> DPP quad_perm (VALU, ~4cyc) replaces both
// ds_bpermute shuffles (~120cyc each) on the critical path. h-pair packing
// for the broadcast uses quad_perm(2,3,0,1): lane 4k holds (h[2k],h[2k+1]),
// read via readlane(pk, 4k). Per-lane G1q word is row*64 + lane (linear).
// Dot trees 4-deep (was 8). Depth-8 rotating register prefetch with clamped
// indices + wave-uniform commit guards inside variable-length chunks.
// ---------------------------------------------------------------------------
__global__ __launch_bounds__(64) void lstm_kernel(
    const uint2* __restrict__ G1q, const float* __restrict__ Whh,
    const int* __restrict__ done, const float* __restrict__ h0,
    const float* __restrict__ c0, unsigned* __restrict__ Y16)
{
  static_assert(BA == 512 && NCHUNK == 16, "index math below assumes 512x16");
  const int lane = threadIdx.x;        // 0..63
  const int u    = lane >> 1;          // 0..31 hidden unit
  const int half = lane & 1;           // 0: (i,g)  1: (f,o)
  const int row  = blockIdx.x & (BA - 1);   // 0..511
  const int ck   = blockIdx.x >> 9;         // 0..15 chunk index
  const int b    = row >> 5;

  // done -> two 64-bit wave-uniform SGPR masks (bit t = done[t,b] != 0)
  unsigned long long dm0 = __ballot(done[lane*Bn + b] != 0);          // t = 0..63
  unsigned long long dm1 = __ballot(done[(lane + 64)*Bn + b] != 0);   // t = 64..127

  // chunk bounds: [s, e). s is a done-reset (or t=0), so state at s is known.
  const int s = (ck == 0) ? 0 : first_done_ge(dm0, dm1, ck * CHUNKW);
  const int e = (ck == NCHUNK - 1) ? Tn
                                   : first_done_ge(dm0, dm1, (ck + 1) * CHUNKW);
  if (s >= e) return;                  // empty chunk

  // Whh rows: gate A = i (half0) / f (half1) = u + 32*half ; gate B = g/o = +64
  pk16x2 wA[16], wB[16];
  const int rwA = u + half*32;
#pragma unroll
  for (int k4 = 0; k4 < 8; ++k4) {
    float4 a  = *(const float4*)&Whh[(rwA     )*HID + k4*4];
    float4 bq = *(const float4*)&Whh[(rwA + 64)*HID + k4*4];
    wA[2*k4+0] = __builtin_amdgcn_cvt_pkrtz(a.x,  a.y);
    wA[2*k4+1] = __builtin_amdgcn_cvt_pkrtz(a.z,  a.w);
    wB[2*k4+0] = __builtin_amdgcn_cvt_pkrtz(bq.x, bq.y);
    wB[2*k4+1] = __builtin_amdgcn_cvt_pkrtz(bq.z, bq.w);
  }

  // initial state: h0/c0 only for the t=0 chunk; other chunks start at a
  // done-reset, where the step itself zero-masks history (h=c=0 consistent).
  float c, h;
  if (ck == 0) { c = c0[row*HID + u]; h = h0[row*HID + u]; }
  else         { c = 0.f;             h = 0.f; }
  unsigned pk = h2bits(__builtin_amdgcn_cvt_pkrtz(h, dpp_quad2(h)));

  // per-half second-activation constants: half0 -> tanh(x)=2*sig(2x)-1,
  // half1 -> sig(x)
  const float sSc = half ? 1.f : 2.f;
  const float m1c = half ? 1.f : 2.f;
  const float m0c = half ? 0.f : -1.f;

  // per-lane 4B gate word, linear in lane: uint index row*64 + lane
  const unsigned* gb = (const unsigned*)G1q + (size_t)row*64 + lane;
  const size_t gstride = (size_t)BA * 64;        // uints per step

  // depth-8 rotating register pipeline (clamped indices at chunk tail)
  unsigned q0 = gb[(size_t)(s                      ) * gstride];
  unsigned q1 = gb[(size_t)((s+1 < e) ? s+1 : e-1) * gstride];
  unsigned q2 = gb[(size_t)((s+2 < e) ? s+2 : e-1) * gstride];
  unsigned q3 = gb[(size_t)((s+3 < e) ? s+3 : e-1) * gstride];
  unsigned q4 = gb[(size_t)((s+4 < e) ? s+4 : e-1) * gstride];
  unsigned q5 = gb[(size_t)((s+5 < e) ? s+5 : e-1) * gstride];
  unsigned q6 = gb[(size_t)((s+6 < e) ? s+6 : e-1) * gstride];
  unsigned q7 = gb[(size_t)((s+7 < e) ? s+7 : e-1) * gstride];

#define LSTM_PHASE(PH, Q)                                                     \
  {                                                                           \
    const int t = tb + (PH);                                                  \
    unsigned cur = Q;                                                         \
    int tpre = t + 8; tpre = (tpre < e) ? tpre : (e - 1);                     \
    Q = gb[(size_t)tpre * gstride];            /* issue before compute */     \
    if (t < e) {                               /* wave-uniform guard */       \
      unsigned long long dbit = (t < 64) ? (dm0 >> t) : (dm1 >> (t - 64));    \
      float m = (dbit & 1ull) ? 0.f : 1.f;                                    \
      unsigned hp[16];                                                        \
      _Pragma("unroll") for (int k = 0; k < 16; ++k)                          \
        hp[k] = __builtin_amdgcn_readlane(pk, 4*k);                           \
      float aA0=0.f, aA1=0.f, aA2=0.f, aA3=0.f;                               \
      float aB0=0.f, aB1=0.f, aB2=0.f, aB3=0.f;                               \
      _Pragma("unroll") for (int k = 0; k < 16; k += 4) {                     \
        pk16x2 h0v = bits2h(hp[k]),   h1v = bits2h(hp[k+1]);                  \
        pk16x2 h2v = bits2h(hp[k+2]), h3v = bits2h(hp[k+3]);                  \
        aA0 = dot2(wA[k],   h0v, aA0); aA1 = dot2(wA[k+1], h1v, aA1);         \
        aA2 = dot2(wA[k+2], h2v, aA2); aA3 = dot2(wA[k+3], h3v, aA3);         \
        aB0 = dot2(wB[k],   h0v, aB0); aB1 = dot2(wB[k+1], h1v, aB1);         \
        aB2 = dot2(wB[k+2], h2v, aB2); aB3 = dot2(wB[k+3], h3v, aB3);         \
      }                                                                       \
      pk16x2 g2 = bits2h(cur);                                                \
      float x0 = fmaf(m, (aA0 + aA1) + (aA2 + aA3), (float)g2.x); /* i|f */   \
      float x1 = fmaf(m, (aB0 + aB1) + (aB2 + aB3), (float)g2.y); /* g|o */   \
      float v0 = fast_sig(x0);                                                \
      float v1 = fmaf(m1c, fast_sig(sSc * x1), m0c);                          \
      float o0 = dpp_swap1(v0);              /* partner = lane^1, VALU */     \
      float o1 = dpp_swap1(v1);                                               \
      float iv = half ? o0 : v0;                                              \
      float fv = half ? v0 : o0;                                              \
      float gv = half ? o1 : v1;                                              \
      float ov = half ? v1 : o1;                                              \
      c = fmaf(fv, m * c, iv * gv);                                           \
      h = ov * fast_tanh(c);                                                  \
      pk = h2bits(__builtin_amdgcn_cvt_pkrtz(h, dpp_quad2(h)));               \
      if ((lane & 3) == 0)                                                    \
        Y16[((size_t)t*BA + row)*16 + (lane >> 2)] = pk;                      \
    }                                                                         \
  }

  for (int tb = s; tb < e; tb += 8) {
    LSTM_PHASE(0, q0)
    LSTM_PHASE(1, q1)
    LSTM_PHASE(2, q2)
    LSTM_PHASE(3, q3)
    LSTM_PHASE(4, q4)
    LSTM_PHASE(5, q5)
    LSTM_PHASE(6, q6)
    LSTM_PHASE(7, q7)
  }
#undef LSTM_PHASE
}

// ---------------------------------------------------------------------------
// Heads: per row, 27 logits (3 heads x 9), log-softmax, entropy, gather,
// product of chosen log-probs. One thread per row; Y (fp16 pairs) read
// directly from global.
// ---------------------------------------------------------------------------
__global__ __launch_bounds__(256) void head_kernel(
    const unsigned* __restrict__ Y16, const float* __restrict__ Wh,
    const float* __restrict__ bh, const int* __restrict__ actions,
    float* __restrict__ out)
{
  __shared__ __align__(16) float whs[27*32];
  __shared__ float bhs[32];
  const int tid = threadIdx.x;
  const int R0 = blockIdx.x * 256;
  for (int i = tid; i < 27*32; i += 256) whs[i] = Wh[i];
  if (tid < 27) bhs[tid] = bh[tid];
  const int row = R0 + tid;
  float yv[32];
#pragma unroll
  for (int i4 = 0; i4 < 4; ++i4) {
    uint4 yw = *(const uint4*)&Y16[(size_t)row*16 + i4*4];
    pk16x2 p0 = bits2h(yw.x), p1 = bits2h(yw.y), p2 = bits2h(yw.z), p3 = bits2h(yw.w);
    yv[i4*8+0] = (float)p0.x; yv[i4*8+1] = (float)p0.y;
    yv[i4*8+2] = (float)p1.x; yv[i4*8+3] = (float)p1.y;
    yv[i4*8+4] = (float)p2.x; yv[i4*8+5] = (float)p2.y;
    yv[i4*8+6] = (float)p3.x; yv[i4*8+7] = (float)p3.y;
  }
  __syncthreads();
  float l[27];
#pragma unroll
  for (int m = 0; m < 27; ++m) {
    float a = bhs[m];
#pragma unroll
    for (int k4 = 0; k4 < 8; ++k4) {
      float4 w4 = *(const float4*)&whs[m*32 + k4*4];   // uniform -> broadcast
      a = fmaf(yv[k4*4+0], w4.x, a);
      a = fmaf(yv[k4*4+1], w4.y, a);
      a = fmaf(yv[k4*4+2], w4.z, a);
      a = fmaf(yv[k4*4+3], w4.w, a);
    }
    l[m] = a;
  }
  float logprob = 1.0f;
#pragma unroll
  for (int kk = 0; kk < 3; ++kk) {
    float mx = l[kk*9];
#pragma unroll
    for (int n = 1; n < 9; ++n) mx = fmaxf(mx, l[kk*9+n]);
    float s = 0.f;
#pragma unroll
    for (int n = 0; n < 9; ++n) s += __expf(l[kk*9+n] - mx);
    float lse = mx + __logf(s);
    float ent = 0.f;
#pragma unroll
    for (int n = 0; n < 9; ++n) {
      float lp = l[kk*9+n] - lse;
      ent -= __expf(lp) * lp;
    }
    int a = actions[row*3 + kk];
    float alp = 0.f;
#pragma unroll
    for (int n = 0; n < 9; ++n) alp = (a == n) ? (l[kk*9+n] - lse) : alp;
    logprob *= alp;
    out[OUT_ENT + row*3 + kk] = ent;     // actions echoed by cvtw_act_kernel
  }
  out[OUT_LP + row] = logprob;
}

extern "C" void kernel_launch(void* const* d_in, const int* in_sizes, int n_in,
                              void* d_out, int out_size, void* d_ws, size_t ws_size,
                              hipStream_t stream)
{
  const float* x       = (const float*)d_in[0];
  const int*   done    = (const int*)  d_in[1];
  const int*   actions = (const int*)  d_in[2];
  const float* W1  = (const float*)d_in[3];
  const float* b1  = (const float*)d_in[4];
  const float* W2  = (const float*)d_in[5];
  const float* b2  = (const float*)d_in[6];
  const float* W3  = (const float*)d_in[7];
  const float* b3  = (const float*)d_in[8];
  const float* Wih = (const float*)d_in[9];
  const float* Whh = (const float*)d_in[10];
  const float* bih = (const float*)d_in[11];
  const float* bhh = (const float*)d_in[12];
  const float* Wh  = (const float*)d_in[13];
  const float* bh  = (const float*)d_in[14];
  const float* h0  = (const float*)d_in[15];
  const float* c0  = (const float*)d_in[16];
  float* out = (float*)d_out;

  uint2* G1q = (uint2*)d_ws;                         // TBA*32 uint2 = 16.8 MB
  unsigned* Y16 = (unsigned*)(G1q + (size_t)TBA*32); // TBA*16 uints =  4.2 MB
  _Float16* W16 = (_Float16*)(Y16 + (size_t)TBA*16); // 128 KB

  cvtw_act_kernel<<<W16_TOT/256 + (TBA*Kh)/256, 256, 0, stream>>>(
      W1, W2, W3, Wih, W16, actions, out);
  mlp_kernel<<<TBA/128, 512, 0, stream>>>(x, W16, b1, b2, b3, bih, bhh, G1q);
  lstm_kernel<<<BA * NCHUNK, 64, 0, stream>>>(G1q, Whh, done, h0, c0, Y16);
  head_kernel<<<TBA/256, 256, 0, stream>>>(Y16, Wh, bh, actions, out);
}

// Round 5
// 170.049 us; speedup vs baseline: 1.1428x; 1.0100x over previous
//
#include <hip/hip_runtime.h>
#include <math.h>

namespace {
constexpr int Tn = 128, Bn = 16, An = 32, OBS = 256, Kh = 3, NACT = 9, HID = 32;
constexpr int TBA = Tn * Bn * An;   // 65536 rows through the MLP
constexpr int BA  = Bn * An;        // 512 LSTM sequences
constexpr int OUT_LP  = TBA * Kh;         // 196608: logprobs start
constexpr int OUT_ENT = TBA * Kh + TBA;   // 262144: entropies start
constexpr int NCHUNK = 16;                // time-chunks per row (done-reset cuts)
constexpr int CHUNKW = Tn / NCHUNK;       // nominal chunk width (8)

// fp16 weight pack offsets (elements)
constexpr int W1_OFF  = 0;       // 128x256
constexpr int W2_OFF  = 32768;   // 128x128
constexpr int W3_OFF  = 49152;   // 64x128
constexpr int WIH_OFF = 57344;   // 128x64
constexpr int W16_TOT = 65536;

typedef __fp16   pk16x2 __attribute__((ext_vector_type(2)));  // builtin-compatible
typedef _Float16 half8v __attribute__((ext_vector_type(8)));
typedef float    f32x4  __attribute__((ext_vector_type(4)));
}

__device__ __forceinline__ float fast_sig(float x) {
  return __builtin_amdgcn_rcpf(1.f + __expf(-x));
}
__device__ __forceinline__ float fast_tanh(float x) {   // 2*sig(2x)-1, saturates safely
  return fmaf(2.f, fast_sig(2.f * x), -1.f);
}
__device__ __forceinline__ unsigned h2bits(pk16x2 h) {
  return __builtin_bit_cast(unsigned, h);
}
__device__ __forceinline__ pk16x2 bits2h(unsigned u) {
  return __builtin_bit_cast(pk16x2, u);
}
__device__ __forceinline__ float dot2(pk16x2 a, pk16x2 b, float c) {
#if __has_builtin(__builtin_amdgcn_fdot2)
  return __builtin_amdgcn_fdot2(a, b, c, false);
#else
  c = fmaf((float)a.x, (float)b.x, c);
  return fmaf((float)a.y, (float)b.y, c);
#endif
}
// swap adjacent lanes (xor 1) via DPP quad_perm(1,0,3,2): VALU, no DS pipe
__device__ __forceinline__ float dpp_swap1(float x) {
  return __uint_as_float((unsigned)__builtin_amdgcn_mov_dpp(
      (int)__float_as_uint(x), 0xB1, 0xF, 0xF, true));
}
// swap lane pairs within quad via DPP quad_perm(2,3,0,1): lane 4m <-> 4m+2 etc.
__device__ __forceinline__ float dpp_quad2(float x) {
  return __uint_as_float((unsigned)__builtin_amdgcn_mov_dpp(
      (int)__float_as_uint(x), 0x4E, 0xF, 0xF, true));
}
// first set bit index >= n in the 128-bit mask {dm0, dm1}; 128 if none.
// n is wave-uniform. Used to find done-reset chunk boundaries.
__device__ __forceinline__ int first_done_ge(unsigned long long dm0,
                                             unsigned long long dm1, int n) {
  unsigned long long m0 = (n < 64) ? (dm0 & (~0ull << n)) : 0ull;
  unsigned long long m1 = (n < 64) ? dm1 : (dm1 & (~0ull << (n - 64)));
  if (m0) return __builtin_ctzll(m0);
  if (m1) return 64 + __builtin_ctzll(m1);
  return 128;
}

// ---------------------------------------------------------------------------
// Weight fp32->fp16 pre-conversion (blocks 0..255) + lstm-setup precompute
// (block 256): lane-coalesced permuted Whh fp16 pairs and per-column done
// bitmasks. v13: the actions echo moved to head_kernel; this grid shrinks
// from 1024 to 257 blocks.
// WhhP layout (u32 pairs): arr A = rows perm(l)=(l>>1)+32*(l&1), arr B =
// perm(l)+64. Index: arr*1024 + k4*128 + l*2 + j, j selects k2=2*k4+j; value
// packs (Whh[row][2*k2], Whh[row][2*k2+1]) with cvt_pkrtz (v12 rounding).
// In lstm, lane l does 8+8 coalesced dwordx2 loads: uint2[k4*64 + l].
// ---------------------------------------------------------------------------
__global__ __launch_bounds__(256) void cvtw_act_kernel(
    const float* __restrict__ W1, const float* __restrict__ W2,
    const float* __restrict__ W3, const float* __restrict__ Wih,
    _Float16* __restrict__ w16, const float* __restrict__ Whh,
    const int* __restrict__ done, unsigned* __restrict__ whhp,
    unsigned long long* __restrict__ dmask)
{
  const int bid = blockIdx.x;
  const int tid = threadIdx.x;
  if (bid < W16_TOT/256) {
    int i = bid * 256 + tid;                    // 0..65535
    float v;
    if (i < W2_OFF)       v = W1[i];
    else if (i < W3_OFF)  v = W2[i - W2_OFF];
    else if (i < WIH_OFF) v = W3[i - W3_OFF];
    else                  v = Wih[i - WIH_OFF];
    w16[i] = (_Float16)v;
  } else {
    // permuted fp16 Whh pairs: 2048 u32 (A then B)
    for (int i = tid; i < 2048; i += 256) {
      int arr = i >> 10;                 // 0 = A (rows rwA), 1 = B (rows +64)
      int r   = i & 1023;
      int k4  = r >> 7;
      int q   = r & 127;
      int l   = q >> 1;
      int j   = q & 1;
      int k2  = 2*k4 + j;
      int row = (l >> 1) + 32*(l & 1) + (arr ? 64 : 0);
      pk16x2 p = __builtin_amdgcn_cvt_pkrtz(Whh[row*HID + 2*k2],
                                            Whh[row*HID + 2*k2 + 1]);
      whhp[i] = h2bits(p);
    }
    // per-column done bitmasks (wave 0 only): bit t = done[t,b] != 0
    if (tid < 64) {
#pragma unroll
      for (int b = 0; b < Bn; ++b) {
        unsigned long long m0 = __ballot(done[tid*Bn + b] != 0);         // t 0..63
        unsigned long long m1 = __ballot(done[(tid + 64)*Bn + b] != 0);  // 64..127
        if (tid == 0) { dmask[2*b] = m0; dmask[2*b + 1] = m1; }
      }
    }
  }
}

// ---------------------------------------------------------------------------
// Fused MLP trunk + LSTM input projection, f16 MFMA (fp32 accumulate).
// v3: 512 threads (8 waves), 128 rows/block, 512 blocks -> halves per-row
// weight-staging traffic and barrier count. LDS 71.7 KB -> 2 blocks/CU.
// ---------------------------------------------------------------------------
template<int ROWS, int WSTR>
__device__ __forceinline__ void stage_wh(const _Float16* __restrict__ Wg, int kofs,
                                         _Float16* __restrict__ wt, int tid)
{
#pragma unroll
  for (int it = 0; it < ROWS/64; ++it) {        // ROWS*8 units / 512 threads
    int idx = tid + it*512;
    int o = idx >> 3, g8 = idx & 7;
    *(half8v*)&wt[o*72 + g8*8] =
        *(const half8v*)&Wg[(size_t)o*WSTR + kofs + g8*8];
  }
}

template<int NOC, int XSTR>
__device__ __forceinline__ void mfma_slab(const _Float16* __restrict__ xsrc,
                                          const _Float16* __restrict__ wt,
                                          int rA, int ln, int quad, f32x4 acc[8])
{
#pragma unroll
  for (int kc = 0; kc < 2; ++kc) {
    half8v a = *(const half8v*)&xsrc[rA*XSTR + kc*32 + quad*8];
#pragma unroll
    for (int oc = 0; oc < NOC; ++oc) {
      half8v b = *(const half8v*)&wt[(oc*16 + ln)*72 + kc*32 + quad*8];
      acc[oc] = __builtin_amdgcn_mfma_f32_16x16x32_f16(a, b, acc[oc], 0, 0, 0);
    }
  }
}

__global__ __launch_bounds__(512) void mlp_kernel(
    const float* __restrict__ x, const _Float16* __restrict__ w16,
    const float* __restrict__ b1, const float* __restrict__ b2,
    const float* __restrict__ b3, const float* __restrict__ bih,
    const float* __restrict__ bhh, uint2* __restrict__ G1q)
{
  __shared__ __align__(16) _Float16 xs[128*72];    // x k-slab; reused for z
  __shared__ __align__(16) _Float16 wt[128*72];    // weight k-slab
  __shared__ __align__(16) _Float16 act[128*136];  // activations (in place)
  const _Float16* W1h  = w16 + W1_OFF;
  const _Float16* W2h  = w16 + W2_OFF;
  const _Float16* W3h  = w16 + W3_OFF;
  const _Float16* Wihh = w16 + WIH_OFF;
  const int tid  = threadIdx.x;                // 0..511
  const int w    = tid >> 6;                   // 0..7
  const int lane = tid & 63;
  const int ln   = lane & 15;
  const int quad = lane >> 4;
  const int rA   = 16*w + ln;                  // 0..127
  const int r0   = 16*w + quad*4;
  const int R0   = blockIdx.x * 128;
  f32x4 acc[8];

  // ---- layer 1: 256 -> 128, tanh (4 k-slabs of 64) ----
#pragma unroll
  for (int oc = 0; oc < 8; ++oc) acc[oc] = (f32x4)0.f;
  for (int kt = 0; kt < 4; ++kt) {
#pragma unroll
    for (int it = 0; it < 2; ++it) {           // stage x slab [128][64] -> fp16
      int idx = tid + it*512;
      int r = idx >> 3, g8 = idx & 7;
      const float* xp = &x[(size_t)(R0 + r)*OBS + kt*64 + g8*8];
      float4 v0 = *(const float4*)xp;
      float4 v1 = *(const float4*)(xp + 4);
      half8v hv = { (_Float16)v0.x, (_Float16)v0.y, (_Float16)v0.z, (_Float16)v0.w,
                    (_Float16)v1.x, (_Float16)v1.y, (_Float16)v1.z, (_Float16)v1.w };
      *(half8v*)&xs[r*72 + g8*8] = hv;
    }
    stage_wh<128, 256>(W1h, kt*64, wt, tid);
    __syncthreads();
    mfma_slab<8, 72>(xs, wt, rA, ln, quad, acc);
    __syncthreads();
  }
#pragma unroll
  for (int oc = 0; oc < 8; ++oc) {
    int o = oc*16 + ln;
    float bv = b1[o];
#pragma unroll
    for (int r = 0; r < 4; ++r)
      act[(r0 + r)*136 + o] = (_Float16)fast_tanh(acc[oc][r] + bv);
  }

  // ---- layer 2: 128 -> 128, tanh ----
#pragma unroll
  for (int oc = 0; oc < 8; ++oc) acc[oc] = (f32x4)0.f;
  for (int kt = 0; kt < 2; ++kt) {
    stage_wh<128, 128>(W2h, kt*64, wt, tid);
    __syncthreads();                            // publishes act writes + wt
    mfma_slab<8, 136>(act + kt*64, wt, rA, ln, quad, acc);
    __syncthreads();
  }
#pragma unroll
  for (int oc = 0; oc < 8; ++oc) {
    int o = oc*16 + ln;
    float bv = b2[o];
#pragma unroll
    for (int r = 0; r < 4; ++r)
      act[(r0 + r)*136 + o] = (_Float16)fast_tanh(acc[oc][r] + bv);
  }

  // ---- layer 3: 128 -> 64, linear -> z into xs buffer ----
#pragma unroll
  for (int oc = 0; oc < 4; ++oc) acc[oc] = (f32x4)0.f;
  for (int kt = 0; kt < 2; ++kt) {
    stage_wh<64, 128>(W3h, kt*64, wt, tid);
    __syncthreads();
    mfma_slab<4, 136>(act + kt*64, wt, rA, ln, quad, acc);
    __syncthreads();
  }
#pragma unroll
  for (int oc = 0; oc < 4; ++oc) {
    int o = oc*16 + ln;
    float bv = b3[o];
#pragma unroll
    for (int r = 0; r < 4; ++r)
      xs[(r0 + r)*72 + o] = (_Float16)(acc[oc][r] + bv);
  }

  // ---- layer 4: z(64) -> 128 gate inputs, all 4 gates of unit u packed ----
#pragma unroll
  for (int oc = 0; oc < 8; ++oc) acc[oc] = (f32x4)0.f;
  stage_wh<128, 64>(Wihh, 0, wt, tid);
  __syncthreads();                              // publishes z writes + wt
  mfma_slab<8, 72>(xs, wt, rA, ln, quad, acc);
#pragma unroll
  for (int p = 0; p < 2; ++p) {
    int ui = p*16 + ln;
    float bi = bih[ui]      + bhh[ui];
    float bf = bih[ui + 32] + bhh[ui + 32];
    float bg = bih[ui + 64] + bhh[ui + 64];
    float bo = bih[ui + 96] + bhh[ui + 96];
#pragma unroll
    for (int r = 0; r < 4; ++r) {
      int n = R0 + r0 + r;
      uint2 q;
      q.x = h2bits(__builtin_amdgcn_cvt_pkrtz(acc[p  ][r] + bi, acc[p+4][r] + bg));
      q.y = h2bits(__builtin_amdgcn_cvt_pkrtz(acc[p+2][r] + bf, acc[p+6][r] + bo));
      G1q[(size_t)n*32 + ui] = q;
    }
  }
}

// ---------------------------------------------------------------------------
// LSTM scan v13: v12 step math + coalesced setup. Per-wave setup previously
// fanned out ~1024 cache-line requests (Whh per-lane row loads: 64 distinct
// lines PER INSTRUCTION; done ballot loads: 64 lines each). With 8192 waves
// that's ~9M line-requests serializing in the per-CU address pipes — the
// measured 26 us wall (invariant v11 vs v12 at equal request count). Now:
// Whh comes from cvtw's lane-permuted WhhP (16 dwordx2, fully dense), done
// masks are precomputed u64 pairs (wave-uniform loads). Step loop unchanged.
// ---------------------------------------------------------------------------
__global__ __launch_bounds__(64) void lstm_kernel(
    const uint2* __restrict__ G1q, const unsigned* __restrict__ whhp,
    const unsigned long long* __restrict__ dmask,
    const float* __restrict__ h0, const float* __restrict__ c0,
    unsigned* __restrict__ Y16)
{
  static_assert(BA == 512 && NCHUNK == 16, "index math below assumes 512x16");
  const int lane = threadIdx.x;        // 0..63
  const int half = lane & 1;           // 0: (i,g)  1: (f,o)
  const int row  = blockIdx.x & (BA - 1);   // 0..511
  const int ck   = blockIdx.x >> 9;         // 0..15 chunk index
  const int b    = row >> 5;

  // wave-uniform done masks (precomputed by cvtw)
  const unsigned long long dm0 = dmask[2*b];
  const unsigned long long dm1 = dmask[2*b + 1];

  // chunk bounds: [s, e). s is a done-reset (or t=0), so state at s is known.
  const int s = (ck == 0) ? 0 : first_done_ge(dm0, dm1, ck * CHUNKW);
  const int e = (ck == NCHUNK - 1) ? Tn
                                   : first_done_ge(dm0, dm1, (ck + 1) * CHUNKW);
  if (s >= e) return;                  // empty chunk

  // Whh pairs, lane-coalesced: wA[2k4+j] = pair j of uint2 at [k4*64 + lane]
  pk16x2 wA[16], wB[16];
  const uint2* wpA = (const uint2*)whhp;         // 512 uint2 (A)
  const uint2* wpB = wpA + 512;                  // 512 uint2 (B)
#pragma unroll
  for (int k4 = 0; k4 < 8; ++k4) {
    uint2 va = wpA[k4*64 + lane];
    uint2 vb = wpB[k4*64 + lane];
    wA[2*k4+0] = bits2h(va.x); wA[2*k4+1] = bits2h(va.y);
    wB[2*k4+0] = bits2h(vb.x); wB[2*k4+1] = bits2h(vb.y);
  }

  // initial state: h0/c0 only for the t=0 chunk; other chunks start at a
  // done-reset, where the step itself zero-masks history (h=c=0 consistent).
  float c, h;
  if (ck == 0) { c = c0[row*HID + (lane >> 1)]; h = h0[row*HID + (lane >> 1)]; }
  else         { c = 0.f;                       h = 0.f; }
  unsigned pk = h2bits(__builtin_amdgcn_cvt_pkrtz(h, dpp_quad2(h)));

  // per-half second-activation constants: half0 -> tanh(x)=2*sig(2x)-1,
  // half1 -> sig(x)
  const float sSc = half ? 1.f : 2.f;
  const float m1c = half ? 1.f : 2.f;
  const float m0c = half ? 0.f : -1.f;

  // per-lane 4B gate word, linear in lane: uint index row*64 + lane
  const unsigned* gb = (const unsigned*)G1q + (size_t)row*64 + lane;
  const size_t gstride = (size_t)BA * 64;        // uints per step

  // depth-8 rotating register pipeline (clamped indices at chunk tail)
  unsigned q0 = gb[(size_t)(s                      ) * gstride];
  unsigned q1 = gb[(size_t)((s+1 < e) ? s+1 : e-1) * gstride];
  unsigned q2 = gb[(size_t)((s+2 < e) ? s+2 : e-1) * gstride];
  unsigned q3 = gb[(size_t)((s+3 < e) ? s+3 : e-1) * gstride];
  unsigned q4 = gb[(size_t)((s+4 < e) ? s+4 : e-1) * gstride];
  unsigned q5 = gb[(size_t)((s+5 < e) ? s+5 : e-1) * gstride];
  unsigned q6 = gb[(size_t)((s+6 < e) ? s+6 : e-1) * gstride];
  unsigned q7 = gb[(size_t)((s+7 < e) ? s+7 : e-1) * gstride];

#define LSTM_PHASE(PH, Q)                                                     \
  {                                                                           \
    const int t = tb + (PH);                                                  \
    unsigned cur = Q;                                                         \
    int tpre = t + 8; tpre = (tpre < e) ? tpre : (e - 1);                     \
    Q = gb[(size_t)tpre * gstride];            /* issue before compute */     \
    if (t < e) {                               /* wave-uniform guard */       \
      unsigned long long dbit = (t < 64) ? (dm0 >> t) : (dm1 >> (t - 64));    \
      float m = (dbit & 1ull) ? 0.f : 1.f;                                    \
      unsigned hp[16];                                                        \
      _Pragma("unroll") for (int k = 0; k < 16; ++k)                          \
        hp[k] = __builtin_amdgcn_readlane(pk, 4*k);                           \
      float aA0=0.f, aA1=0.f, aA2=0.f, aA3=0.f;                               \
      float aB0=0.f, aB1=0.f, aB2=0.f, aB3=0.f;                               \
      _Pragma("unroll") for (int k = 0; k < 16; k += 4) {                     \
        pk16x2 h0v = bits2h(hp[k]),   h1v = bits2h(hp[k+1]);                  \
        pk16x2 h2v = bits2h(hp[k+2]), h3v = bits2h(hp[k+3]);                  \
        aA0 = dot2(wA[k],   h0v, aA0); aA1 = dot2(wA[k+1], h1v, aA1);         \
        aA2 = dot2(wA[k+2], h2v, aA2); aA3 = dot2(wA[k+3], h3v, aA3);         \
        aB0 = dot2(wB[k],   h0v, aB0); aB1 = dot2(wB[k+1], h1v, aB1);         \
        aB2 = dot2(wB[k+2], h2v, aB2); aB3 = dot2(wB[k+3], h3v, aB3);         \
      }                                                                       \
      pk16x2 g2 = bits2h(cur);                                                \
      float x0 = fmaf(m, (aA0 + aA1) + (aA2 + aA3), (float)g2.x); /* i|f */   \
      float x1 = fmaf(m, (aB0 + aB1) + (aB2 + aB3), (float)g2.y); /* g|o */   \
      float v0 = fast_sig(x0);                                                \
      float v1 = fmaf(m1c, fast_sig(sSc * x1), m0c);                          \
      float o0 = dpp_swap1(v0);              /* partner = lane^1, VALU */     \
      float o1 = dpp_swap1(v1);                                               \
      float iv = half ? o0 : v0;                                              \
      float fv = half ? v0 : o0;                                              \
      float gv = half ? o1 : v1;                                              \
      float ov = half ? v1 : o1;                                              \
      c = fmaf(fv, m * c, iv * gv);                                           \
      h = ov * fast_tanh(c);                                                  \
      pk = h2bits(__builtin_amdgcn_cvt_pkrtz(h, dpp_quad2(h)));               \
      if ((lane & 3) == 0)                                                    \
        Y16[((size_t)t*BA + row)*16 + (lane >> 2)] = pk;                      \
    }                                                                         \
  }

  for (int tb = s; tb < e; tb += 8) {
    LSTM_PHASE(0, q0)
    LSTM_PHASE(1, q1)
    LSTM_PHASE(2, q2)
    LSTM_PHASE(3, q3)
    LSTM_PHASE(4, q4)
    LSTM_PHASE(5, q5)
    LSTM_PHASE(6, q6)
    LSTM_PHASE(7, q7)
  }
#undef LSTM_PHASE
}

// ---------------------------------------------------------------------------
// Heads: per row, 27 logits (3 heads x 9), log-softmax, entropy, gather,
// product of chosen log-probs. One thread per row; Y (fp16 pairs) read
// directly from global. v13: also echoes actions into out[0..196607]
// (out[row*3+kk] = actions[row*3+kk]) — moved here from cvtw.
// ---------------------------------------------------------------------------
__global__ __launch_bounds__(256) void head_kernel(
    const unsigned* __restrict__ Y16, const float* __restrict__ Wh,
    const float* __restrict__ bh, const int* __restrict__ actions,
    float* __restrict__ out)
{
  __shared__ __align__(16) float whs[27*32];
  __shared__ float bhs[32];
  const int tid = threadIdx.x;
  const int R0 = blockIdx.x * 256;
  for (int i = tid; i < 27*32; i += 256) whs[i] = Wh[i];
  if (tid < 27) bhs[tid] = bh[tid];
  const int row = R0 + tid;
  float yv[32];
#pragma unroll
  for (int i4 = 0; i4 < 4; ++i4) {
    uint4 yw = *(const uint4*)&Y16[(size_t)row*16 + i4*4];
    pk16x2 p0 = bits2h(yw.x), p1 = bits2h(yw.y), p2 = bits2h(yw.z), p3 = bits2h(yw.w);
    yv[i4*8+0] = (float)p0.x; yv[i4*8+1] = (float)p0.y;
    yv[i4*8+2] = (float)p1.x; yv[i4*8+3] = (float)p1.y;
    yv[i4*8+4] = (float)p2.x; yv[i4*8+5] = (float)p2.y;
    yv[i4*8+6] = (float)p3.x; yv[i4*8+7] = (float)p3.y;
  }
  __syncthreads();
  float l[27];
#pragma unroll
  for (int m = 0; m < 27; ++m) {
    float a = bhs[m];
#pragma unroll
    for (int k4 = 0; k4 < 8; ++k4) {
      float4 w4 = *(const float4*)&whs[m*32 + k4*4];   // uniform -> broadcast
      a = fmaf(yv[k4*4+0], w4.x, a);
      a = fmaf(yv[k4*4+1], w4.y, a);
      a = fmaf(yv[k4*4+2], w4.z, a);
      a = fmaf(yv[k4*4+3], w4.w, a);
    }
    l[m] = a;
  }
  float logprob = 1.0f;
#pragma unroll
  for (int kk = 0; kk < 3; ++kk) {
    float mx = l[kk*9];
#pragma unroll
    for (int n = 1; n < 9; ++n) mx = fmaxf(mx, l[kk*9+n]);
    float s = 0.f;
#pragma unroll
    for (int n = 0; n < 9; ++n) s += __expf(l[kk*9+n] - mx);
    float lse = mx + __logf(s);
    float ent = 0.f;
#pragma unroll
    for (int n = 0; n < 9; ++n) {
      float lp = l[kk*9+n] - lse;
      ent -= __expf(lp) * lp;
    }
    int a = actions[row*3 + kk];
    out[row*3 + kk] = (float)a;          // actions echo (moved from cvtw)
    float alp = 0.f;
#pragma unroll
    for (int n = 0; n < 9; ++n) alp = (a == n) ? (l[kk*9+n] - lse) : alp;
    logprob *= alp;
    out[OUT_ENT + row*3 + kk] = ent;
  }
  out[OUT_LP + row] = logprob;
}

extern "C" void kernel_launch(void* const* d_in, const int* in_sizes, int n_in,
                              void* d_out, int out_size, void* d_ws, size_t ws_size,
                              hipStream_t stream)
{
  const float* x       = (const float*)d_in[0];
  const int*   done    = (const int*)  d_in[1];
  const int*   actions = (const int*)  d_in[2];
  const float* W1  = (const float*)d_in[3];
  const float* b1  = (const float*)d_in[4];
  const float* W2  = (const float*)d_in[5];
  const float* b2  = (const float*)d_in[6];
  const float* W3  = (const float*)d_in[7];
  const float* b3  = (const float*)d_in[8];
  const float* Wih = (const float*)d_in[9];
  const float* Whh = (const float*)d_in[10];
  const float* bih = (const float*)d_in[11];
  const float* bhh = (const float*)d_in[12];
  const float* Wh  = (const float*)d_in[13];
  const float* bh  = (const float*)d_in[14];
  const float* h0  = (const float*)d_in[15];
  const float* c0  = (const float*)d_in[16];
  float* out = (float*)d_out;

  uint2* G1q = (uint2*)d_ws;                          // TBA*32 uint2 = 16.8 MB
  unsigned* Y16 = (unsigned*)(G1q + (size_t)TBA*32);  // TBA*16 uints =  4.2 MB
  _Float16* W16 = (_Float16*)(Y16 + (size_t)TBA*16);  // 128 KB
  unsigned* WhhP = (unsigned*)(W16 + W16_TOT);        // 2048 u32 = 8 KB
  unsigned long long* Dm = (unsigned long long*)(WhhP + 2048);  // 32 u64

  cvtw_act_kernel<<<W16_TOT/256 + 1, 256, 0, stream>>>(
      W1, W2, W3, Wih, W16, Whh, done, WhhP, Dm);
  mlp_kernel<<<TBA/128, 512, 0, stream>>>(x, W16, b1, b2, b3, bih, bhh, G1q);
  lstm_kernel<<<BA * NCHUNK, 64, 0, stream>>>(G1q, WhhP, Dm, h0, c0, Y16);
  head_kernel<<<TBA/256, 256, 0, stream>>>(Y16, Wh, bh, actions, out);
}

// Round 6
// 167.978 us; speedup vs baseline: 1.1568x; 1.0123x over previous
//
#include <hip/hip_runtime.h>
#include <math.h>

namespace {
constexpr int Tn = 128, Bn = 16, An = 32, OBS = 256, Kh = 3, NACT = 9, HID = 32;
constexpr int TBA = Tn * Bn * An;   // 65536 rows through the MLP
constexpr int BA  = Bn * An;        // 512 LSTM sequences
constexpr int OUT_LP  = TBA * Kh;         // 196608: logprobs start
constexpr int OUT_ENT = TBA * Kh + TBA;   // 262144: entropies start
constexpr int NCHUNK = 32;                // time-chunks per row (done-reset cuts)
constexpr int CHUNKW = Tn / NCHUNK;       // nominal chunk width (4)

// fp16 weight pack offsets (elements)
constexpr int W1_OFF  = 0;       // 128x256
constexpr int W2_OFF  = 32768;   // 128x128
constexpr int W3_OFF  = 49152;   // 64x128
constexpr int WIH_OFF = 57344;   // 128x64
constexpr int W16_TOT = 65536;

typedef __fp16   pk16x2 __attribute__((ext_vector_type(2)));  // builtin-compatible
typedef _Float16 half8v __attribute__((ext_vector_type(8)));
typedef float    f32x4  __attribute__((ext_vector_type(4)));
}

__device__ __forceinline__ float fast_sig(float x) {
  return __builtin_amdgcn_rcpf(1.f + __expf(-x));
}
__device__ __forceinline__ float fast_tanh(float x) {   // 2*sig(2x)-1, saturates safely
  return fmaf(2.f, fast_sig(2.f * x), -1.f);
}
__device__ __forceinline__ unsigned h2bits(pk16x2 h) {
  return __builtin_bit_cast(unsigned, h);
}
__device__ __forceinline__ pk16x2 bits2h(unsigned u) {
  return __builtin_bit_cast(pk16x2, u);
}
// first set bit index >= n in the 128-bit mask {dm0, dm1}; 128 if none.
// n is wave-uniform. Used to find done-reset chunk boundaries.
__device__ __forceinline__ int first_done_ge(unsigned long long dm0,
                                             unsigned long long dm1, int n) {
  unsigned long long m0 = (n < 64) ? (dm0 & (~0ull << n)) : 0ull;
  unsigned long long m1 = (n < 64) ? dm1 : (dm1 & (~0ull << (n - 64)));
  if (m0) return __builtin_ctzll(m0);
  if (m1) return 64 + __builtin_ctzll(m1);
  return 128;
}

// ---------------------------------------------------------------------------
// Weight fp32->fp16 pre-conversion (blocks 0..255) + lstm precompute (block
// 256): Whh as per-lane MFMA A-fragments + per-column done bitmasks.
// A-fragment layout (matches mlp's verified usage of mfma_f32_16x16x32_f16):
// A[m][k] at lane l element j: m = l&15, k = (l>>4)*8 + j. For gate-tile tl
// (gates 16tl..16tl+15): WT[tl*512 + l*8 + j] = Whh[16tl + (l&15)][(l>>4)*8+j].
// ---------------------------------------------------------------------------
__global__ __launch_bounds__(256) void cvtw_act_kernel(
    const float* __restrict__ W1, const float* __restrict__ W2,
    const float* __restrict__ W3, const float* __restrict__ Wih,
    _Float16* __restrict__ w16, const float* __restrict__ Whh,
    const int* __restrict__ done, _Float16* __restrict__ wt16,
    unsigned long long* __restrict__ dmask)
{
  const int bid = blockIdx.x;
  const int tid = threadIdx.x;
  if (bid < W16_TOT/256) {
    int i = bid * 256 + tid;                    // 0..65535
    float v;
    if (i < W2_OFF)       v = W1[i];
    else if (i < W3_OFF)  v = W2[i - W2_OFF];
    else if (i < WIH_OFF) v = W3[i - W3_OFF];
    else                  v = Wih[i - WIH_OFF];
    w16[i] = (_Float16)v;
  } else {
    // Whh A-fragments: 8 tiles x 64 lanes x 8 halves = 4096
    for (int i = tid; i < 4096; i += 256) {
      int tl = i >> 9, rem = i & 511, l = rem >> 3, j = rem & 7;
      int gate = 16*tl + (l & 15);
      int unit = ((l >> 4) << 3) + j;
      wt16[i] = (_Float16)Whh[gate*HID + unit];
    }
    // per-column done bitmasks (wave 0 only): bit t = done[t,b] != 0
    if (tid < 64) {
#pragma unroll
      for (int b = 0; b < Bn; ++b) {
        unsigned long long m0 = __ballot(done[tid*Bn + b] != 0);         // t 0..63
        unsigned long long m1 = __ballot(done[(tid + 64)*Bn + b] != 0);  // 64..127
        if (tid == 0) { dmask[2*b] = m0; dmask[2*b + 1] = m1; }
      }
    }
  }
}

// ---------------------------------------------------------------------------
// Fused MLP trunk + LSTM input projection, f16 MFMA (fp32 accumulate).
// 512 threads (8 waves), 128 rows/block, 512 blocks.
// ---------------------------------------------------------------------------
template<int ROWS, int WSTR>
__device__ __forceinline__ void stage_wh(const _Float16* __restrict__ Wg, int kofs,
                                         _Float16* __restrict__ wt, int tid)
{
#pragma unroll
  for (int it = 0; it < ROWS/64; ++it) {        // ROWS*8 units / 512 threads
    int idx = tid + it*512;
    int o = idx >> 3, g8 = idx & 7;
    *(half8v*)&wt[o*72 + g8*8] =
        *(const half8v*)&Wg[(size_t)o*WSTR + kofs + g8*8];
  }
}

template<int NOC, int XSTR>
__device__ __forceinline__ void mfma_slab(const _Float16* __restrict__ xsrc,
                                          const _Float16* __restrict__ wt,
                                          int rA, int ln, int quad, f32x4 acc[8])
{
#pragma unroll
  for (int kc = 0; kc < 2; ++kc) {
    half8v a = *(const half8v*)&xsrc[rA*XSTR + kc*32 + quad*8];
#pragma unroll
    for (int oc = 0; oc < NOC; ++oc) {
      half8v b = *(const half8v*)&wt[(oc*16 + ln)*72 + kc*32 + quad*8];
      acc[oc] = __builtin_amdgcn_mfma_f32_16x16x32_f16(a, b, acc[oc], 0, 0, 0);
    }
  }
}

__global__ __launch_bounds__(512) void mlp_kernel(
    const float* __restrict__ x, const _Float16* __restrict__ w16,
    const float* __restrict__ b1, const float* __restrict__ b2,
    const float* __restrict__ b3, const float* __restrict__ bih,
    const float* __restrict__ bhh, uint2* __restrict__ G1q)
{
  __shared__ __align__(16) _Float16 xs[128*72];    // x k-slab; reused for z
  __shared__ __align__(16) _Float16 wt[128*72];    // weight k-slab
  __shared__ __align__(16) _Float16 act[128*136];  // activations (in place)
  const _Float16* W1h  = w16 + W1_OFF;
  const _Float16* W2h  = w16 + W2_OFF;
  const _Float16* W3h  = w16 + W3_OFF;
  const _Float16* Wihh = w16 + WIH_OFF;
  const int tid  = threadIdx.x;                // 0..511
  const int w    = tid >> 6;                   // 0..7
  const int lane = tid & 63;
  const int ln   = lane & 15;
  const int quad = lane >> 4;
  const int rA   = 16*w + ln;                  // 0..127
  const int r0   = 16*w + quad*4;
  const int R0   = blockIdx.x * 128;
  f32x4 acc[8];

  // ---- layer 1: 256 -> 128, tanh (4 k-slabs of 64) ----
#pragma unroll
  for (int oc = 0; oc < 8; ++oc) acc[oc] = (f32x4)0.f;
  for (int kt = 0; kt < 4; ++kt) {
#pragma unroll
    for (int it = 0; it < 2; ++it) {           // stage x slab [128][64] -> fp16
      int idx = tid + it*512;
      int r = idx >> 3, g8 = idx & 7;
      const float* xp = &x[(size_t)(R0 + r)*OBS + kt*64 + g8*8];
      float4 v0 = *(const float4*)xp;
      float4 v1 = *(const float4*)(xp + 4);
      half8v hv = { (_Float16)v0.x, (_Float16)v0.y, (_Float16)v0.z, (_Float16)v0.w,
                    (_Float16)v1.x, (_Float16)v1.y, (_Float16)v1.z, (_Float16)v1.w };
      *(half8v*)&xs[r*72 + g8*8] = hv;
    }
    stage_wh<128, 256>(W1h, kt*64, wt, tid);
    __syncthreads();
    mfma_slab<8, 72>(xs, wt, rA, ln, quad, acc);
    __syncthreads();
  }
#pragma unroll
  for (int oc = 0; oc < 8; ++oc) {
    int o = oc*16 + ln;
    float bv = b1[o];
#pragma unroll
    for (int r = 0; r < 4; ++r)
      act[(r0 + r)*136 + o] = (_Float16)fast_tanh(acc[oc][r] + bv);
  }

  // ---- layer 2: 128 -> 128, tanh ----
#pragma unroll
  for (int oc = 0; oc < 8; ++oc) acc[oc] = (f32x4)0.f;
  for (int kt = 0; kt < 2; ++kt) {
    stage_wh<128, 128>(W2h, kt*64, wt, tid);
    __syncthreads();                            // publishes act writes + wt
    mfma_slab<8, 136>(act + kt*64, wt, rA, ln, quad, acc);
    __syncthreads();
  }
#pragma unroll
  for (int oc = 0; oc < 8; ++oc) {
    int o = oc*16 + ln;
    float bv = b2[o];
#pragma unroll
    for (int r = 0; r < 4; ++r)
      act[(r0 + r)*136 + o] = (_Float16)fast_tanh(acc[oc][r] + bv);
  }

  // ---- layer 3: 128 -> 64, linear -> z into xs buffer ----
#pragma unroll
  for (int oc = 0; oc < 4; ++oc) acc[oc] = (f32x4)0.f;
  for (int kt = 0; kt < 2; ++kt) {
    stage_wh<64, 128>(W3h, kt*64, wt, tid);
    __syncthreads();
    mfma_slab<4, 136>(act + kt*64, wt, rA, ln, quad, acc);
    __syncthreads();
  }
#pragma unroll
  for (int oc = 0; oc < 4; ++oc) {
    int o = oc*16 + ln;
    float bv = b3[o];
#pragma unroll
    for (int r = 0; r < 4; ++r)
      xs[(r0 + r)*72 + o] = (_Float16)(acc[oc][r] + bv);
  }

  // ---- layer 4: z(64) -> 128 gate inputs, all 4 gates of unit u packed ----
#pragma unroll
  for (int oc = 0; oc < 8; ++oc) acc[oc] = (f32x4)0.f;
  stage_wh<128, 64>(Wihh, 0, wt, tid);
  __syncthreads();                              // publishes z writes + wt
  mfma_slab<8, 72>(xs, wt, rA, ln, quad, acc);
#pragma unroll
  for (int p = 0; p < 2; ++p) {
    int ui = p*16 + ln;
    float bi = bih[ui]      + bhh[ui];
    float bf = bih[ui + 32] + bhh[ui + 32];
    float bg = bih[ui + 64] + bhh[ui + 64];
    float bo = bih[ui + 96] + bhh[ui + 96];
#pragma unroll
    for (int r = 0; r < 4; ++r) {
      int n = R0 + r0 + r;
      uint2 q;
      q.x = h2bits(__builtin_amdgcn_cvt_pkrtz(acc[p  ][r] + bi, acc[p+4][r] + bg));
      q.y = h2bits(__builtin_amdgcn_cvt_pkrtz(acc[p+2][r] + bf, acc[p+6][r] + bo));
      G1q[(size_t)n*32 + ui] = q;
    }
  }
}

// ---------------------------------------------------------------------------
// LSTM scan v14: MFMA formulation, 16 rows/wave. Per step:
//   gates^T[128 x 16 rows] = Whh-tiles (static A-frags) x h^T (B) + G1 (C).
// 8x mfma_f32_16x16x32_f16, no readlane/SGPR broadcast. Fragment maps are
// the same as mlp_kernel's verified usage:
//   A[m= l&15][k=(l>>4)*8+j], B[k=(l>>4)*8+j][n= l&15], C[m=(l>>4)*4+r][n= l&15].
// Tiles: i = acc[p], f = acc[2+p], g = acc[4+p], o = acc[6+p] (p = unit>>4;
// gate = 16*tl + ...). Lane (ln,q) ends the step holding h'[units {4q+r,
// 16+4q+r}][row R0+ln]; next B needs h[row ln][units 8q..8q+7] — exchange
// only among lanes {ln, ln+16, ln+32, ln+48}: 8 ds_bpermute + 4 selects.
// G1 loads: 4x dwordx4/lane/step from the unchanged G1q layout (x=(i,g),
// y=(f,o)). done: zero B + zero c (wave-uniform). Y16 format unchanged.
// NCHUNK=32 done-reset chunks -> 1024 blocks x 64 threads.
// ---------------------------------------------------------------------------
__global__ __launch_bounds__(64) void lstm_kernel(
    const uint2* __restrict__ G1q, const _Float16* __restrict__ wt16,
    const unsigned long long* __restrict__ dmask,
    const float* __restrict__ h0, const float* __restrict__ c0,
    unsigned* __restrict__ Y16)
{
  static_assert(BA == 512 && NCHUNK == 32, "index math below assumes 512x32");
  const int lane = threadIdx.x;        // 0..63
  const int ln   = lane & 15;          // row within 16-row group / B,C column
  const int q    = lane >> 4;          // quad
  const int rg   = blockIdx.x & 31;    // row group (16 rows)
  const int ck   = blockIdx.x >> 5;    // 0..31 chunk index
  const int R0   = rg * 16;
  const int b    = R0 >> 5;            // batch column (wave-uniform)

  const unsigned long long dm0 = dmask[2*b];
  const unsigned long long dm1 = dmask[2*b + 1];

  // chunk bounds: [s, e). s is a done-reset (or t=0), so state at s is known.
  const int s = (ck == 0) ? 0 : first_done_ge(dm0, dm1, ck * CHUNKW);
  const int e = (ck == NCHUNK - 1) ? Tn
                                   : first_done_ge(dm0, dm1, (ck + 1) * CHUNKW);
  if (s >= e) return;                  // empty chunk

  // static Whh A-fragments (8 gate-tiles)
  half8v wA0 = *(const half8v*)&wt16[0*512 + lane*8];
  half8v wA1 = *(const half8v*)&wt16[1*512 + lane*8];
  half8v wA2 = *(const half8v*)&wt16[2*512 + lane*8];
  half8v wA3 = *(const half8v*)&wt16[3*512 + lane*8];
  half8v wA4 = *(const half8v*)&wt16[4*512 + lane*8];
  half8v wA5 = *(const half8v*)&wt16[5*512 + lane*8];
  half8v wA6 = *(const half8v*)&wt16[6*512 + lane*8];
  half8v wA7 = *(const half8v*)&wt16[7*512 + lane*8];

  const float4 z4 = {0.f, 0.f, 0.f, 0.f};
  float4 cs0, cs1;                     // c state: units 4q+r / 16+4q+r, row R0+ln
  unsigned w0, w1, w2, w3;             // packed h pairs (even,odd units)
  if (ck == 0) {
    const float* hp = &h0[(size_t)(R0 + ln)*HID + 4*q];
    const float* cp = &c0[(size_t)(R0 + ln)*HID + 4*q];
    float4 ha = *(const float4*)hp;
    float4 hb = *(const float4*)(hp + 16);
    cs0 = *(const float4*)cp;
    cs1 = *(const float4*)(cp + 16);
    w0 = h2bits(__builtin_amdgcn_cvt_pkrtz(ha.x, ha.y));
    w1 = h2bits(__builtin_amdgcn_cvt_pkrtz(ha.z, ha.w));
    w2 = h2bits(__builtin_amdgcn_cvt_pkrtz(hb.x, hb.y));
    w3 = h2bits(__builtin_amdgcn_cvt_pkrtz(hb.z, hb.w));
  } else {
    cs0 = z4; cs1 = z4;
    w0 = w1 = w2 = w3 = 0u;
  }

  // bpermute byte addresses (static): even-source and odd-source lanes
  const int aA = (ln + ((q & 1) << 5)) << 2;
  const int aB = aA + (16 << 2);
  const bool loq = (q < 2);

  // G1 base: uint2 index n*32 + 16p + 4q, n = t*512 + R0 + ln
  const uint2* gb = G1q + ((size_t)(R0 + ln) * 32 + 4*q);
  const size_t gstep = (size_t)BA * 32;          // uint2 per t

#define LOADG(T, A0, A1, A2, A3)                                  \
  { const uint2* p_ = gb + (size_t)(T) * gstep;                   \
    A0 = *(const uint4*)(p_);      A1 = *(const uint4*)(p_ + 2);  \
    A2 = *(const uint4*)(p_ + 16); A3 = *(const uint4*)(p_ + 18); }

  uint4 rc0, rc1, rc2, rc3;
  LOADG(s, rc0, rc1, rc2, rc3);

  for (int t = s; t < e; ++t) {
    int tn = (t + 1 < e) ? t + 1 : e - 1;
    uint4 rn0, rn1, rn2, rn3;
    LOADG(tn, rn0, rn1, rn2, rn3);             // prefetch next step

    unsigned long long dbit = (t < 64) ? (dm0 >> t) : (dm1 >> (t - 64));
    unsigned b0, b1, b2, b3;
    if (dbit & 1ull) {                         // reset: h=0 (B=0), c=0
      b0 = b1 = b2 = b3 = 0u;
      cs0 = z4; cs1 = z4;
    } else {                                   // build B from prev h packs
      unsigned e0 = (unsigned)__builtin_amdgcn_ds_bpermute(aA, (int)w0);
      unsigned e1 = (unsigned)__builtin_amdgcn_ds_bpermute(aA, (int)w1);
      unsigned e2 = (unsigned)__builtin_amdgcn_ds_bpermute(aA, (int)w2);
      unsigned e3 = (unsigned)__builtin_amdgcn_ds_bpermute(aA, (int)w3);
      unsigned o0 = (unsigned)__builtin_amdgcn_ds_bpermute(aB, (int)w0);
      unsigned o1 = (unsigned)__builtin_amdgcn_ds_bpermute(aB, (int)w1);
      unsigned o2 = (unsigned)__builtin_amdgcn_ds_bpermute(aB, (int)w2);
      unsigned o3 = (unsigned)__builtin_amdgcn_ds_bpermute(aB, (int)w3);
      b0 = loq ? e0 : e2;  b1 = loq ? e1 : e3;
      b2 = loq ? o0 : o2;  b3 = loq ? o1 : o3;
    }
    uint4 bu; bu.x = b0; bu.y = b1; bu.z = b2; bu.w = b3;
    half8v B = __builtin_bit_cast(half8v, bu);

    // unpack G1 -> C inits (i,f,g,o per p, reg). x=(i,g) y=(f,o)
    f32x4 ci0, cf0, cg0, co0, ci1, cf1, cg1, co1;
    {
      pk16x2 ig, fo;
      ig = bits2h(rc0.x); fo = bits2h(rc0.y);
      ci0[0] = ig.x; cg0[0] = ig.y; cf0[0] = fo.x; co0[0] = fo.y;
      ig = bits2h(rc0.z); fo = bits2h(rc0.w);
      ci0[1] = ig.x; cg0[1] = ig.y; cf0[1] = fo.x; co0[1] = fo.y;
      ig = bits2h(rc1.x); fo = bits2h(rc1.y);
      ci0[2] = ig.x; cg0[2] = ig.y; cf0[2] = fo.x; co0[2] = fo.y;
      ig = bits2h(rc1.z); fo = bits2h(rc1.w);
      ci0[3] = ig.x; cg0[3] = ig.y; cf0[3] = fo.x; co0[3] = fo.y;
      ig = bits2h(rc2.x); fo = bits2h(rc2.y);
      ci1[0] = ig.x; cg1[0] = ig.y; cf1[0] = fo.x; co1[0] = fo.y;
      ig = bits2h(rc2.z); fo = bits2h(rc2.w);
      ci1[1] = ig.x; cg1[1] = ig.y; cf1[1] = fo.x; co1[1] = fo.y;
      ig = bits2h(rc3.x); fo = bits2h(rc3.y);
      ci1[2] = ig.x; cg1[2] = ig.y; cf1[2] = fo.x; co1[2] = fo.y;
      ig = bits2h(rc3.z); fo = bits2h(rc3.w);
      ci1[3] = ig.x; cg1[3] = ig.y; cf1[3] = fo.x; co1[3] = fo.y;
    }

    // gates^T = Whh x h^T + G1
    f32x4 ai0 = __builtin_amdgcn_mfma_f32_16x16x32_f16(wA0, B, ci0, 0, 0, 0);
    f32x4 ai1 = __builtin_amdgcn_mfma_f32_16x16x32_f16(wA1, B, ci1, 0, 0, 0);
    f32x4 af0 = __builtin_amdgcn_mfma_f32_16x16x32_f16(wA2, B, cf0, 0, 0, 0);
    f32x4 af1 = __builtin_amdgcn_mfma_f32_16x16x32_f16(wA3, B, cf1, 0, 0, 0);
    f32x4 ag0 = __builtin_amdgcn_mfma_f32_16x16x32_f16(wA4, B, cg0, 0, 0, 0);
    f32x4 ag1 = __builtin_amdgcn_mfma_f32_16x16x32_f16(wA5, B, cg1, 0, 0, 0);
    f32x4 ao0 = __builtin_amdgcn_mfma_f32_16x16x32_f16(wA6, B, co0, 0, 0, 0);
    f32x4 ao1 = __builtin_amdgcn_mfma_f32_16x16x32_f16(wA7, B, co1, 0, 0, 0);

    // activations + state update (v13 formulas; c pre-zeroed at resets)
    f32x4 hva, hvb;
#pragma unroll
    for (int r = 0; r < 4; ++r) {
      float iv = fast_sig(ai0[r]);
      float fv = fast_sig(af0[r]);
      float gv = fast_tanh(ag0[r]);
      float ov = fast_sig(ao0[r]);
      float cc = fmaf(fv, cs0[r], iv * gv);
      cs0[r] = cc;
      hva[r] = ov * fast_tanh(cc);
    }
#pragma unroll
    for (int r = 0; r < 4; ++r) {
      float iv = fast_sig(ai1[r]);
      float fv = fast_sig(af1[r]);
      float gv = fast_tanh(ag1[r]);
      float ov = fast_sig(ao1[r]);
      float cc = fmaf(fv, cs1[r], iv * gv);
      cs1[r] = cc;
      hvb[r] = ov * fast_tanh(cc);
    }

    // pack h' pairs (even,odd units) and store Y16 (format unchanged)
    w0 = h2bits(__builtin_amdgcn_cvt_pkrtz(hva[0], hva[1]));
    w1 = h2bits(__builtin_amdgcn_cvt_pkrtz(hva[2], hva[3]));
    w2 = h2bits(__builtin_amdgcn_cvt_pkrtz(hvb[0], hvb[1]));
    w3 = h2bits(__builtin_amdgcn_cvt_pkrtz(hvb[2], hvb[3]));
    unsigned* yb = &Y16[((size_t)t*BA + R0 + ln)*16 + 2*q];
    uint2 ya; ya.x = w0; ya.y = w1;
    uint2 yc; yc.x = w2; yc.y = w3;
    *(uint2*)yb       = ya;            // words 2q, 2q+1   (units 4q..4q+3)
    *(uint2*)(yb + 8) = yc;            // words 8+2q, +1   (units 16+4q..)

    rc0 = rn0; rc1 = rn1; rc2 = rn2; rc3 = rn3;
  }
#undef LOADG
}

// ---------------------------------------------------------------------------
// Heads: per row, 27 logits (3 heads x 9), log-softmax, entropy, gather,
// product of chosen log-probs. One thread per row; Y (fp16 pairs) read
// directly from global. Echoes actions into out[0..196607].
// ---------------------------------------------------------------------------
__global__ __launch_bounds__(256) void head_kernel(
    const unsigned* __restrict__ Y16, const float* __restrict__ Wh,
    const float* __restrict__ bh, const int* __restrict__ actions,
    float* __restrict__ out)
{
  __shared__ __align__(16) float whs[27*32];
  __shared__ float bhs[32];
  const int tid = threadIdx.x;
  const int R0 = blockIdx.x * 256;
  for (int i = tid; i < 27*32; i += 256) whs[i] = Wh[i];
  if (tid < 27) bhs[tid] = bh[tid];
  const int row = R0 + tid;
  float yv[32];
#pragma unroll
  for (int i4 = 0; i4 < 4; ++i4) {
    uint4 yw = *(const uint4*)&Y16[(size_t)row*16 + i4*4];
    pk16x2 p0 = bits2h(yw.x), p1 = bits2h(yw.y), p2 = bits2h(yw.z), p3 = bits2h(yw.w);
    yv[i4*8+0] = (float)p0.x; yv[i4*8+1] = (float)p0.y;
    yv[i4*8+2] = (float)p1.x; yv[i4*8+3] = (float)p1.y;
    yv[i4*8+4] = (float)p2.x; yv[i4*8+5] = (float)p2.y;
    yv[i4*8+6] = (float)p3.x; yv[i4*8+7] = (float)p3.y;
  }
  __syncthreads();
  float l[27];
#pragma unroll
  for (int m = 0; m < 27; ++m) {
    float a = bhs[m];
#pragma unroll
    for (int k4 = 0; k4 < 8; ++k4) {
      float4 w4 = *(const float4*)&whs[m*32 + k4*4];   // uniform -> broadcast
      a = fmaf(yv[k4*4+0], w4.x, a);
      a = fmaf(yv[k4*4+1], w4.y, a);
      a = fmaf(yv[k4*4+2], w4.z, a);
      a = fmaf(yv[k4*4+3], w4.w, a);
    }
    l[m] = a;
  }
  float logprob = 1.0f;
#pragma unroll
  for (int kk = 0; kk < 3; ++kk) {
    float mx = l[kk*9];
#pragma unroll
    for (int n = 1; n < 9; ++n) mx = fmaxf(mx, l[kk*9+n]);
    float s = 0.f;
#pragma unroll
    for (int n = 0; n < 9; ++n) s += __expf(l[kk*9+n] - mx);
    float lse = mx + __logf(s);
    float ent = 0.f;
#pragma unroll
    for (int n = 0; n < 9; ++n) {
      float lp = l[kk*9+n] - lse;
      ent -= __expf(lp) * lp;
    }
    int a = actions[row*3 + kk];
    out[row*3 + kk] = (float)a;          // actions echo
    float alp = 0.f;
#pragma unroll
    for (int n = 0; n < 9; ++n) alp = (a == n) ? (l[kk*9+n] - lse) : alp;
    logprob *= alp;
    out[OUT_ENT + row*3 + kk] = ent;
  }
  out[OUT_LP + row] = logprob;
}

extern "C" void kernel_launch(void* const* d_in, const int* in_sizes, int n_in,
                              void* d_out, int out_size, void* d_ws, size_t ws_size,
                              hipStream_t stream)
{
  const float* x       = (const float*)d_in[0];
  const int*   done    = (const int*)  d_in[1];
  const int*   actions = (const int*)  d_in[2];
  const float* W1  = (const float*)d_in[3];
  const float* b1  = (const float*)d_in[4];
  const float* W2  = (const float*)d_in[5];
  const float* b2  = (const float*)d_in[6];
  const float* W3  = (const float*)d_in[7];
  const float* b3  = (const float*)d_in[8];
  const float* Wih = (const float*)d_in[9];
  const float* Whh = (const float*)d_in[10];
  const float* bih = (const float*)d_in[11];
  const float* bhh = (const float*)d_in[12];
  const float* Wh  = (const float*)d_in[13];
  const float* bh  = (const float*)d_in[14];
  const float* h0  = (const float*)d_in[15];
  const float* c0  = (const float*)d_in[16];
  float* out = (float*)d_out;

  uint2* G1q = (uint2*)d_ws;                          // TBA*32 uint2 = 16.8 MB
  unsigned* Y16 = (unsigned*)(G1q + (size_t)TBA*32);  // TBA*16 uints =  4.2 MB
  _Float16* W16 = (_Float16*)(Y16 + (size_t)TBA*16);  // 128 KB
  _Float16* WT16 = W16 + W16_TOT;                     // 4096 halves = 8 KB
  unsigned long long* Dm = (unsigned long long*)(WT16 + 4096);  // 32 u64

  cvtw_act_kernel<<<W16_TOT/256 + 1, 256, 0, stream>>>(
      W1, W2, W3, Wih, W16, Whh, done, WT16, Dm);
  mlp_kernel<<<TBA/128, 512, 0, stream>>>(x, W16, b1, b2, b3, bih, bhh, G1q);
  lstm_kernel<<<32 * NCHUNK, 64, 0, stream>>>(G1q, WT16, Dm, h0, c0, Y16);
  head_kernel<<<TBA/256, 256, 0, stream>>>(Y16, Wh, bh, actions, out);
}